// Round 4
// baseline (996.824 us; speedup 1.0000x reference)
//
#include <hip/hip_runtime.h>
#include <hip/hip_bf16.h>
#include <stdint.h>

// HierarchicalGNN forward, FP32 in/out, MFMA bf16 GEMMs, CSR-gather GAT (no f32 atomics).
// h=relu(x@Wp+bp); two GATConv(+selfloops, softmax-per-dst) -> LN -> relu;
// concat @ Wf -> LN -> L2-normalize.
// N=200000, E=200000/dir (avg degree ~1), IN=HID=256, HEADS=4, C=64, OUT=128.
// Fusions: att scores in dir-GEMM epilogue; bias+LN+L2norm in final-GEMM epilogue;
// softmax inline in gat_gather (lanes 0-3 serial, deg~1).

typedef __attribute__((ext_vector_type(8))) short bf16x8;
typedef __attribute__((ext_vector_type(4))) short bf16x4;
typedef __attribute__((ext_vector_type(4))) float f32x4;

#define HID 256
#define HEADS 4
#define CH 64

__device__ __forceinline__ float wred(float v) {
    #pragma unroll
    for (int o = 32; o > 0; o >>= 1) v += __shfl_xor(v, o, 64);
    return v;
}
__device__ __forceinline__ float red16(float v) {   // sum within 16-lane group
    #pragma unroll
    for (int o = 1; o < 16; o <<= 1) v += __shfl_xor(v, o, 64);
    return v;
}
__device__ __forceinline__ float bf2f(short s) {
    return __uint_as_float(((unsigned)(unsigned short)s) << 16);
}
__device__ __forceinline__ float sel4(float a0, float a1, float a2, float a3, int h) {
    return h == 0 ? a0 : (h == 1 ? a1 : (h == 2 ? a2 : a3));
}

// async global->LDS, 16B per lane (global_load_lds_dwordx4).
__device__ __forceinline__ void gload_lds16(const void* g, void* l) {
    __builtin_amdgcn_global_load_lds(
        reinterpret_cast<const __attribute__((address_space(1))) uint32_t*>(
            reinterpret_cast<uintptr_t>(g)),
        reinterpret_cast<__attribute__((address_space(3))) uint32_t*>(
            reinterpret_cast<uintptr_t>(l)),
        16, 0, 0);
}

// ---------------- f32 -> bf16 convert (x8 vectorized) ----------------
__global__ __launch_bounds__(256) void cvt_bf16(const float* __restrict__ src,
                                                __hip_bfloat16* __restrict__ dst, long n8) {
    long i = (long)blockIdx.x * 256 + threadIdx.x;   // i indexes groups of 8
    if (i >= n8) return;
    f32x4 v0 = *(const f32x4*)(src + i * 8);
    f32x4 v1 = *(const f32x4*)(src + i * 8 + 4);
    __hip_bfloat16 o[8];
    o[0] = __float2bfloat16(v0[0]); o[1] = __float2bfloat16(v0[1]);
    o[2] = __float2bfloat16(v0[2]); o[3] = __float2bfloat16(v0[3]);
    o[4] = __float2bfloat16(v1[0]); o[5] = __float2bfloat16(v1[1]);
    o[6] = __float2bfloat16(v1[2]); o[7] = __float2bfloat16(v1[3]);
    *(bf16x8*)((short*)dst + i * 8) = *(const bf16x8*)o;
}

// ---------------- transpose+convert W[KI,KO] f32 -> Wt[KO,KI] bf16 ----------------
__global__ void transpose_w(const float* __restrict__ W,
                            __hip_bfloat16* __restrict__ Wt, int KI, int KO) {
    int idx = blockIdx.x * 256 + threadIdx.x;
    if (idx >= KI * KO) return;
    int k = idx / KO, j = idx % KO;
    Wt[(long)j * KI + k] = __float2bfloat16(W[idx]);
}

// ---------------- tiled MFMA GEMM: C[N,BN] = A[N,KI] @ Bt[BN,KI]^T ----------------
// m97 structure: BM=128, BK=32, LDS-staged A/B via global_load_lds_dwordx4.
// MODE 0: +bias/relu -> bf16 out (projection GEMM)
// MODE 1: bf16 out + fused a_src/a_dst scores (dir GEMMs; each wave's 64 cols = 1 head)
// MODE 2: fused +bias -> LN(128) -> L2-normalize -> f32 out (final GEMM, BN=128)
template<int BN, int MODE>
__global__ __launch_bounds__(512) void gemm_tiled(
    const __hip_bfloat16* __restrict__ A0, const __hip_bfloat16* __restrict__ A1,
    int lda, int kSplit,
    const __hip_bfloat16* __restrict__ Bt, int KI,
    const float* __restrict__ bias, int doRelu,
    __hip_bfloat16* __restrict__ outB, float* __restrict__ outF,
    const float* __restrict__ asrcW, const float* __restrict__ adstW,
    float* __restrict__ aS, float* __restrict__ aD,
    const float* __restrict__ gw, const float* __restrict__ bw, int N) {

    constexpr int WN = BN / 64;          // waves along N (4 or 2)
    constexpr int WM = 8 / WN;           // waves along M (2 or 4)
    constexpr int MR = (128 / WM) / 16;  // m-frags per wave (4 or 2)

    __shared__ __align__(16) __hip_bfloat16 sA[128 * 32];   // [row][k] 64B rows
    __shared__ __align__(16) __hip_bfloat16 sB[BN * 32];    // [col][k] 64B rows
    __shared__ float sRed[MODE == 2 ? 128 * 4 : 4];         // LN s1/s2 partials
    __shared__ float sN2[MODE == 2 ? 128 * 2 : 2];          // L2 partials

    int tid = threadIdx.x;
    int wv = tid >> 6, ln = tid & 63;
    int m = ln & 15, q = ln >> 4;
    long row0 = (long)blockIdx.x * 128;
    int wr = (wv / WN) * (128 / WM);
    int wc = (wv % WN) * 64;

    f32x4 acc[MR][4];
    #pragma unroll
    for (int mi = 0; mi < MR; ++mi)
        #pragma unroll
        for (int t = 0; t < 4; ++t) acc[mi][t] = (f32x4){0.f, 0.f, 0.f, 0.f};

    int oA = tid * 16;
    long rowA = row0 + (oA >> 6);
    if (rowA >= N) rowA = N - 1;         // clamp tail loads (dup reads, safe)
    long aOff = rowA * lda + ((oA & 63) >> 1);

    for (int k0 = 0; k0 < KI; k0 += 32) {
        const __hip_bfloat16* Ab = (k0 < kSplit) ? A0 + k0 : A1 + (k0 - kSplit);
        __syncthreads();
        gload_lds16(Ab + aOff, (char*)sA + oA);
        #pragma unroll
        for (int j = 0; j < BN / 128; ++j) {
            int o = j * 8192 + tid * 16;
            const __hip_bfloat16* src = Bt + (long)(o >> 6) * KI + k0 + ((o & 63) >> 1);
            gload_lds16(src, (char*)sB + o);
        }
        __syncthreads();

        bf16x8 af[MR], bfr[4];
        #pragma unroll
        for (int mi = 0; mi < MR; ++mi)
            af[mi] = *(const bf16x8*)((const char*)sA + ((wr + mi * 16 + m) << 6) + q * 16);
        #pragma unroll
        for (int t = 0; t < 4; ++t)
            bfr[t] = *(const bf16x8*)((const char*)sB + ((wc + t * 16 + m) << 6) + q * 16);
        #pragma unroll
        for (int mi = 0; mi < MR; ++mi)
            #pragma unroll
            for (int t = 0; t < 4; ++t)
                acc[mi][t] = __builtin_amdgcn_mfma_f32_16x16x32_bf16(af[mi], bfr[t],
                                                                     acc[mi][t], 0, 0, 0);
    }

    if constexpr (MODE != 2) {
        #pragma unroll
        for (int mi = 0; mi < MR; ++mi) {
            #pragma unroll
            for (int t = 0; t < 4; ++t) {
                int col = wc + t * 16 + m;
                float bv = bias ? bias[col] : 0.f;
                #pragma unroll
                for (int r = 0; r < 4; ++r) {
                    long row = row0 + wr + mi * 16 + q * 4 + r;
                    if (row < N) {
                        float v = acc[mi][t][r] + bv;
                        if (doRelu) v = fmaxf(v, 0.f);
                        outB[row * BN + col] = __float2bfloat16(v);
                    }
                }
            }
        }
    }

    if constexpr (MODE == 1) {
        // fused attention scores: wave's 64 cols = head h; reduce over 16 m-lanes.
        int h = wc >> 6;
        f32x4 sw, dw;
        #pragma unroll
        for (int t = 0; t < 4; ++t) {
            sw[t] = asrcW[wc + t * 16 + m];
            dw[t] = adstW[wc + t * 16 + m];
        }
        #pragma unroll
        for (int mi = 0; mi < MR; ++mi) {
            #pragma unroll
            for (int r = 0; r < 4; ++r) {
                float ps = acc[mi][0][r] * sw[0] + acc[mi][1][r] * sw[1]
                         + acc[mi][2][r] * sw[2] + acc[mi][3][r] * sw[3];
                float pd = acc[mi][0][r] * dw[0] + acc[mi][1][r] * dw[1]
                         + acc[mi][2][r] * dw[2] + acc[mi][3][r] * dw[3];
                ps = red16(ps); pd = red16(pd);
                long row = row0 + wr + mi * 16 + q * 4 + r;
                if (m == 0 && row < N) {
                    aS[row * 4 + h] = ps;
                    aD[row * 4 + h] = pd;
                }
            }
        }
    }

    if constexpr (MODE == 2) {
        // fused +bias -> LN(128) -> L2norm -> f32 out. Block covers full 128-col rows.
        float vv[MR][4][4];
        float gcol[4], bcol[4];
        #pragma unroll
        for (int t = 0; t < 4; ++t) {
            int col = wc + t * 16 + m;
            float bb = bias[col];
            gcol[t] = gw[col]; bcol[t] = bw[col];
            #pragma unroll
            for (int mi = 0; mi < MR; ++mi)
                #pragma unroll
                for (int r = 0; r < 4; ++r) vv[mi][t][r] = acc[mi][t][r] + bb;
        }
        int wcid = wc >> 6;
        #pragma unroll
        for (int mi = 0; mi < MR; ++mi) {
            #pragma unroll
            for (int r = 0; r < 4; ++r) {
                float s1 = vv[mi][0][r] + vv[mi][1][r] + vv[mi][2][r] + vv[mi][3][r];
                float s2 = vv[mi][0][r] * vv[mi][0][r] + vv[mi][1][r] * vv[mi][1][r]
                         + vv[mi][2][r] * vv[mi][2][r] + vv[mi][3][r] * vv[mi][3][r];
                s1 = red16(s1); s2 = red16(s2);
                if (m == 0) {
                    int lrow = wr + mi * 16 + q * 4 + r;
                    sRed[lrow * 4 + wcid * 2 + 0] = s1;
                    sRed[lrow * 4 + wcid * 2 + 1] = s2;
                }
            }
        }
        __syncthreads();
        #pragma unroll
        for (int mi = 0; mi < MR; ++mi) {
            #pragma unroll
            for (int r = 0; r < 4; ++r) {
                int lrow = wr + mi * 16 + q * 4 + r;
                float S1 = sRed[lrow * 4 + 0] + sRed[lrow * 4 + 2];
                float S2 = sRed[lrow * 4 + 1] + sRed[lrow * 4 + 3];
                float mean = S1 * (1.f / 128.f);
                float var = S2 * (1.f / 128.f) - mean * mean;
                float inv = rsqrtf(fmaxf(var, 0.f) + 1e-5f);
                float n2 = 0.f;
                #pragma unroll
                for (int t = 0; t < 4; ++t) {
                    float y = (vv[mi][t][r] - mean) * inv * gcol[t] + bcol[t];
                    vv[mi][t][r] = y;
                    n2 += y * y;
                }
                n2 = red16(n2);
                if (m == 0) sN2[lrow * 2 + wcid] = n2;
            }
        }
        __syncthreads();
        #pragma unroll
        for (int mi = 0; mi < MR; ++mi) {
            #pragma unroll
            for (int r = 0; r < 4; ++r) {
                int lrow = wr + mi * 16 + q * 4 + r;
                long row = row0 + lrow;
                float nrm = sqrtf(sN2[lrow * 2] + sN2[lrow * 2 + 1]);
                float sc = 1.f / fmaxf(nrm, 1e-12f);
                if (row < N) {
                    #pragma unroll
                    for (int t = 0; t < 4; ++t)
                        outF[row * 128 + wc + t * 16 + m] = vv[mi][t][r] * sc;
                }
            }
        }
    }
}

// ---------------- CSR build ----------------
__global__ __launch_bounds__(256) void hist_dst(const int* __restrict__ ei, int E,
                                                int* __restrict__ cnt) {
    int e = blockIdx.x * 256 + threadIdx.x;
    if (e < E) atomicAdd(&cnt[ei[E + e]], 1);
}

__global__ __launch_bounds__(256) void scan1(const int* __restrict__ cnt,
                                             int* __restrict__ offpart,
                                             int* __restrict__ bsum, int n) {
    int t = threadIdx.x, i = blockIdx.x * 256 + t;
    int lane = t & 63, w = t >> 6;
    int v = (i < n) ? cnt[i] : 0;
    int inc = v;
    #pragma unroll
    for (int o = 1; o < 64; o <<= 1) {
        int u = __shfl_up(inc, o, 64);
        if (lane >= o) inc += u;
    }
    __shared__ int wsum[4];
    if (lane == 63) wsum[w] = inc;
    __syncthreads();
    int wadd = 0;
    #pragma unroll
    for (int k = 0; k < 4; ++k) if (k < w) wadd += wsum[k];
    if (i < n) offpart[i] = inc - v + wadd;
    if (t == 255) bsum[blockIdx.x] = inc + wadd;
}

__global__ __launch_bounds__(256) void scan2(const int* __restrict__ bsum,
                                             int* __restrict__ btot, int nb) {
    int t = threadIdx.x, lane = t & 63, w = t >> 6;
    int loc[4]; int s = 0;
    #pragma unroll
    for (int k = 0; k < 4; ++k) {
        int idx = t * 4 + k;
        int v = (idx < nb) ? bsum[idx] : 0;
        loc[k] = s; s += v;
    }
    int inc = s;
    #pragma unroll
    for (int o = 1; o < 64; o <<= 1) {
        int u = __shfl_up(inc, o, 64);
        if (lane >= o) inc += u;
    }
    __shared__ int wsum[4];
    if (lane == 63) wsum[w] = inc;
    __syncthreads();
    int wadd = 0;
    #pragma unroll
    for (int k = 0; k < 4; ++k) if (k < w) wadd += wsum[k];
    int excl = inc - s + wadd;
    #pragma unroll
    for (int k = 0; k < 4; ++k) {
        int idx = t * 4 + k;
        if (idx < nb) btot[idx] = excl + loc[k];
    }
}

__global__ __launch_bounds__(256) void finalize_off(const int* __restrict__ offpart,
                                                    const int* __restrict__ btot,
                                                    int* __restrict__ off, int n, int E) {
    int i = blockIdx.x * 256 + threadIdx.x;
    if (i < n) off[i] = offpart[i] + btot[i >> 8];
    if (i == 0) off[n] = E;
}

__global__ __launch_bounds__(256) void scatter_src(const int* __restrict__ ei, int E,
                                                   const int* __restrict__ off,
                                                   int* __restrict__ cur,
                                                   int* __restrict__ esrc) {
    int e = blockIdx.x * 256 + threadIdx.x;
    if (e >= E) return;
    int d = ei[E + e];
    int pos = off[d] + atomicAdd(&cur[d], 1);
    esrc[pos] = ei[e];
}

// ---------------- fused GAT: inline softmax + gather + bias + LN + relu ----------------
// wave per dst node; lanes 0-3 compute per-head max/denominator serially (avg deg ~1),
// broadcast via shfl; all lanes then do the alpha-weighted gather.
__global__ __launch_bounds__(256) void gat_gather(
    const int* __restrict__ off, const int* __restrict__ esrc,
    const float* __restrict__ a_s, const float* __restrict__ a_d,
    const __hip_bfloat16* __restrict__ hw,
    const float* __restrict__ bias, const float* __restrict__ g,
    const float* __restrict__ b,
    __hip_bfloat16* __restrict__ out, int N) {
    int lane = threadIdx.x & 63;
    long d = (long)blockIdx.x * 4 + (threadIdx.x >> 6);
    if (d >= N) return;
    int beg = off[d], end = off[d + 1];
    f32x4 adv = *(const f32x4*)(a_d + 4 * d);
    f32x4 asd = *(const f32x4*)(a_s + 4 * d);
    int hh = lane & 3;
    float adh_l = sel4(adv[0], adv[1], adv[2], adv[3], hh);
    float ash_l = sel4(asd[0], asd[1], asd[2], asd[3], hh);
    float es_l = ash_l + adh_l; es_l = es_l > 0.f ? es_l : 0.2f * es_l;
    float m_l = es_l, sum_l = 1.f;
    if (lane < 4) {   // serial per-head softmax stats (deg ~1)
        for (int j = beg; j < end; ++j) {
            int s = esrc[j];
            float e = a_s[4 * (long)s + lane] + adh_l;
            e = e > 0.f ? e : 0.2f * e;
            m_l = fmaxf(m_l, e);
        }
        sum_l = __expf(es_l - m_l);
        for (int j = beg; j < end; ++j) {
            int s = esrc[j];
            float e = a_s[4 * (long)s + lane] + adh_l;
            e = e > 0.f ? e : 0.2f * e;
            sum_l += __expf(e - m_l);
        }
    }
    int h4 = lane >> 4;
    float mh = __shfl(m_l, h4, 64);
    float rsh = 1.f / __shfl(sum_l, h4, 64);
    float adh = sel4(adv[0], adv[1], adv[2], adv[3], h4);
    float esh = sel4(asd[0], asd[1], asd[2], asd[3], h4) + adh;
    esh = esh > 0.f ? esh : 0.2f * esh;
    int c0 = lane * 4;
    float acc0, acc1, acc2, acc3;
    {   // self loop
        float alpha = __expf(esh - mh) * rsh;
        bf16x4 hv = *(const bf16x4*)(hw + d * HID + c0);
        acc0 = alpha * bf2f(hv[0]); acc1 = alpha * bf2f(hv[1]);
        acc2 = alpha * bf2f(hv[2]); acc3 = alpha * bf2f(hv[3]);
    }
    for (int j = beg; j < end; ++j) {
        int s = esrc[j];                       // uniform across wave
        float as_h = a_s[4 * (long)s + h4];
        float e = as_h + adh; e = e > 0.f ? e : 0.2f * e;
        float alpha = __expf(e - mh) * rsh;
        bf16x4 hv = *(const bf16x4*)(hw + (long)s * HID + c0);
        acc0 += alpha * bf2f(hv[0]); acc1 += alpha * bf2f(hv[1]);
        acc2 += alpha * bf2f(hv[2]); acc3 += alpha * bf2f(hv[3]);
    }
    // fused bias + LN + relu
    f32x4 bi = *(const f32x4*)(bias + c0);
    acc0 += bi[0]; acc1 += bi[1]; acc2 += bi[2]; acc3 += bi[3];
    float mean = wred(acc0 + acc1 + acc2 + acc3) * (1.f / 256.f);
    acc0 -= mean; acc1 -= mean; acc2 -= mean; acc3 -= mean;
    float var = wred(acc0 * acc0 + acc1 * acc1 + acc2 * acc2 + acc3 * acc3) * (1.f / 256.f);
    float inv = rsqrtf(var + 1e-5f);
    f32x4 gv = *(const f32x4*)(g + c0);
    f32x4 bv = *(const f32x4*)(b + c0);
    __hip_bfloat16 t0 = __float2bfloat16(fmaxf(acc0 * inv * gv[0] + bv[0], 0.f));
    __hip_bfloat16 t1 = __float2bfloat16(fmaxf(acc1 * inv * gv[1] + bv[1], 0.f));
    __hip_bfloat16 t2 = __float2bfloat16(fmaxf(acc2 * inv * gv[2] + bv[2], 0.f));
    __hip_bfloat16 t3 = __float2bfloat16(fmaxf(acc3 * inv * gv[3] + bv[3], 0.f));
    __hip_bfloat16* orow = out + d * HID + c0;
    orow[0] = t0; orow[1] = t1; orow[2] = t2; orow[3] = t3;
}

extern "C" void kernel_launch(void* const* d_in, const int* in_sizes, int n_in,
                              void* d_out, int out_size, void* d_ws, size_t ws_size,
                              hipStream_t stream) {
    const float* x      = (const float*)d_in[0];
    const int*   ei_bu  = (const int*)d_in[1];
    const int*   ei_td  = (const int*)d_in[2];
    const float* Wp     = (const float*)d_in[3];
    const float* bp     = (const float*)d_in[4];
    const float* W_bu   = (const float*)d_in[5];
    const float* asrc_bu= (const float*)d_in[6];
    const float* adst_bu= (const float*)d_in[7];
    const float* bias_bu= (const float*)d_in[8];
    const float* W_td   = (const float*)d_in[9];
    const float* asrc_td= (const float*)d_in[10];
    const float* adst_td= (const float*)d_in[11];
    const float* bias_td= (const float*)d_in[12];
    const float* Wf     = (const float*)d_in[13];
    const float* bfv    = (const float*)d_in[14];
    const float* g_bu   = (const float*)d_in[15];
    const float* b_bu   = (const float*)d_in[16];
    const float* g_td   = (const float*)d_in[17];
    const float* b_td   = (const float*)d_in[18];
    const float* g_out  = (const float*)d_in[19];
    const float* b_out  = (const float*)d_in[20];

    const int N = in_sizes[0] / HID;   // 200000
    const int E = in_sizes[1] / 2;     // 200000

    char* ws = (char*)d_ws;
    size_t off0 = 0;
    auto take = [&](size_t bytes) -> char* {
        char* p = ws + off0;
        off0 += (bytes + 255) & ~(size_t)255;
        return p;
    };
    __hip_bfloat16* xbf   = (__hip_bfloat16*)take((size_t)N * HID * 2); // aliased as hw later
    __hip_bfloat16* h_buf = (__hip_bfloat16*)take((size_t)N * HID * 2);
    __hip_bfloat16* xbu   = (__hip_bfloat16*)take((size_t)N * HID * 2);
    __hip_bfloat16* xtd   = (__hip_bfloat16*)take((size_t)N * HID * 2);
    float* a_s   = (float*)take((size_t)N * 16);
    float* a_d   = (float*)take((size_t)N * 16);
    int* cnt     = (int*)take((size_t)N * 4);   // cnt and cur adjacent -> one memset
    int* cur     = (int*)take((size_t)N * 4);
    int* offpart = (int*)take((size_t)N * 4);
    int* offarr  = (int*)take((size_t)(N + 1) * 4);
    int* esrc    = (int*)take((size_t)E * 4);
    int* bsum    = (int*)take(1024 * 4);
    int* btot    = (int*)take(1024 * 4);
    __hip_bfloat16* Wpt  = (__hip_bfloat16*)take(256 * 256 * 2);
    __hip_bfloat16* Wbut = (__hip_bfloat16*)take(256 * 256 * 2);
    __hip_bfloat16* Wtdt = (__hip_bfloat16*)take(256 * 256 * 2);
    __hip_bfloat16* Wft  = (__hip_bfloat16*)take(512 * 128 * 2);
    __hip_bfloat16* hw = xbf;  // xbf dead after first GEMM

    transpose_w<<<(256 * 256 + 255) / 256, 256, 0, stream>>>(Wp, Wpt, 256, 256);
    transpose_w<<<(256 * 256 + 255) / 256, 256, 0, stream>>>(W_bu, Wbut, 256, 256);
    transpose_w<<<(256 * 256 + 255) / 256, 256, 0, stream>>>(W_td, Wtdt, 256, 256);
    transpose_w<<<(512 * 128 + 255) / 256, 256, 0, stream>>>(Wf, Wft, 512, 128);
    long nx8 = (long)N * HID / 8;
    cvt_bf16<<<(nx8 + 255) / 256, 256, 0, stream>>>(x, xbf, nx8);

    int gm = (N + 127) / 128;

    // h = relu(x @ Wp + bp)
    gemm_tiled<256, 0><<<gm, 512, 0, stream>>>(xbf, xbf, HID, HID, Wpt, HID,
                                               bp, 1, h_buf, nullptr,
                                               nullptr, nullptr, nullptr, nullptr,
                                               nullptr, nullptr, N);

    const int* eis[2] = {ei_bu, ei_td};
    const __hip_bfloat16* Wts[2] = {Wbut, Wtdt};
    const float* asrcs[2] = {asrc_bu, asrc_td};
    const float* adsts[2] = {adst_bu, adst_td};
    const float* biases[2]= {bias_bu, bias_td};
    const float* gs[2]    = {g_bu, g_td};
    const float* bs[2]    = {b_bu, b_td};
    __hip_bfloat16* xouts[2] = {xbu, xtd};

    int egrid = (E + 255) / 256;
    int ngrid = (N + 255) / 256;
    int nb = (N + 255) / 256;
    for (int dir = 0; dir < 2; ++dir) {
        // hw = h @ W  (+ fused a_src/a_dst scores)
        gemm_tiled<256, 1><<<gm, 512, 0, stream>>>(h_buf, h_buf, HID, HID, Wts[dir], HID,
                                                   nullptr, 0, hw, nullptr,
                                                   asrcs[dir], adsts[dir], a_s, a_d,
                                                   nullptr, nullptr, N);
        // CSR build
        hipMemsetAsync(cnt, 0, (size_t)N * 8, stream);   // cnt + cur (adjacent)
        hist_dst<<<egrid, 256, 0, stream>>>(eis[dir], E, cnt);
        scan1<<<nb, 256, 0, stream>>>(cnt, offpart, bsum, N);
        scan2<<<1, 256, 0, stream>>>(bsum, btot, nb);
        finalize_off<<<ngrid, 256, 0, stream>>>(offpart, btot, offarr, N, E);
        scatter_src<<<egrid, 256, 0, stream>>>(eis[dir], E, offarr, cur, esrc);
        // inline softmax + gather + bias + LN + relu
        gat_gather<<<(N + 3) / 4, 256, 0, stream>>>(offarr, esrc, a_s, a_d, hw,
                                                    biases[dir], gs[dir], bs[dir],
                                                    xouts[dir], N);
    }

    // final: out = L2norm(LN([xbu|xtd] @ Wf + bf)) fully fused
    gemm_tiled<128, 2><<<gm, 512, 0, stream>>>(xbu, xtd, HID, HID, Wft, 512,
                                               bfv, 0, nullptr, (float*)d_out,
                                               nullptr, nullptr, nullptr, nullptr,
                                               g_out, b_out, N);
}

// Round 5
// 955.154 us; speedup vs baseline: 1.0436x; 1.0436x over previous
//
#include <hip/hip_runtime.h>
#include <hip/hip_bf16.h>
#include <stdint.h>

// HierarchicalGNN forward, FP32 in/out, MFMA bf16 GEMMs, CSR-gather GAT (no f32 atomics).
// h=relu(x@Wp+bp); two GATConv(+selfloops, softmax-per-dst) -> LN -> relu;
// concat @ Wf -> LN -> L2-normalize.
// N=200000, E=200000/dir (avg degree ~1), IN=HID=256, HEADS=4, C=64, OUT=128.
// Structure: f32->bf16 fused into GEMM1 A-staging; both dir projections in ONE BN=512
// GEMM (fused att scores per wave=head,dir); thread-per-node softmax (att_alpha);
// gat_gather 4 nodes/wave (16 lanes x 16ch); final GEMM fused bias+LN+L2norm.

typedef __attribute__((ext_vector_type(8))) short bf16x8;
typedef __attribute__((ext_vector_type(4))) short bf16x4;
typedef __attribute__((ext_vector_type(4))) float f32x4;

#define HID 256

__device__ __forceinline__ float red16(float v) {   // sum within 16-lane group
    #pragma unroll
    for (int o = 1; o < 16; o <<= 1) v += __shfl_xor(v, o, 64);
    return v;
}
__device__ __forceinline__ float bf2f(short s) {
    return __uint_as_float(((unsigned)(unsigned short)s) << 16);
}

// async global->LDS, 16B per lane (global_load_lds_dwordx4).
__device__ __forceinline__ void gload_lds16(const void* g, void* l) {
    __builtin_amdgcn_global_load_lds(
        reinterpret_cast<const __attribute__((address_space(1))) uint32_t*>(
            reinterpret_cast<uintptr_t>(g)),
        reinterpret_cast<__attribute__((address_space(3))) uint32_t*>(
            reinterpret_cast<uintptr_t>(l)),
        16, 0, 0);
}

// ---------------- transpose+convert W[KI,KO] f32 -> Wt[KO,KI] bf16 ----------------
__global__ void transpose_w(const float* __restrict__ W,
                            __hip_bfloat16* __restrict__ Wt, int KI, int KO) {
    int idx = blockIdx.x * 256 + threadIdx.x;
    if (idx >= KI * KO) return;
    int k = idx / KO, j = idx % KO;
    Wt[(long)j * KI + k] = __float2bfloat16(W[idx]);
}

// ---------------- tiled MFMA GEMM: C[N,BN] = A[N,KI] @ Bt[BN,KI]^T ----------------
// BM=128, BK=32, LDS-staged; B via global_load_lds_dwordx4; A via gload (CVT=0) or
// reg-staged f32->bf16 (CVT=1). 512 threads = 8 waves.
// MODE 0: +bias/relu -> bf16 out
// MODE 1: bf16 out + fused a_src/a_dst scores (BN=512: wave's 64 cols = 1 head, 1 dir)
// MODE 2: fused +bias -> LN(128) -> L2-normalize -> f32 out (BN=128)
template<int BN, int MODE, int CVT>
__global__ __launch_bounds__(512) void gemm_tiled(
    const float* __restrict__ Af, const __hip_bfloat16* __restrict__ Ab, int lda,
    const __hip_bfloat16* __restrict__ Bt, int KI,
    const float* __restrict__ bias, int doRelu,
    __hip_bfloat16* __restrict__ outB, float* __restrict__ outF,
    const float* __restrict__ asrc0, const float* __restrict__ adst0,
    const float* __restrict__ asrc1, const float* __restrict__ adst1,
    float* __restrict__ aS0, float* __restrict__ aD0,
    float* __restrict__ aS1, float* __restrict__ aD1,
    const float* __restrict__ gw, const float* __restrict__ bw, int N) {

    constexpr int WN = BN / 64;          // waves along N (8 / 4 / 2)
    constexpr int WM = 8 / WN;           // waves along M (1 / 2 / 4)
    constexpr int MR = (128 / WM) / 16;  // m-frags per wave (8 / 4 / 2)

    __shared__ __align__(16) __hip_bfloat16 sA[128 * 32];   // [row][k] 64B rows
    __shared__ __align__(16) __hip_bfloat16 sB[BN * 32];    // [col][k] 64B rows
    __shared__ float sRed[MODE == 2 ? 128 * 4 : 4];
    __shared__ float sN2[MODE == 2 ? 128 * 2 : 2];

    int tid = threadIdx.x;
    int wv = tid >> 6, ln = tid & 63;
    int m = ln & 15, q = ln >> 4;
    long row0 = (long)blockIdx.x * 128;
    int wr = (wv / WN) * (128 / WM);
    int wc = (wv % WN) * 64;

    f32x4 acc[MR][4];
    #pragma unroll
    for (int mi = 0; mi < MR; ++mi)
        #pragma unroll
        for (int t = 0; t < 4; ++t) acc[mi][t] = (f32x4){0.f, 0.f, 0.f, 0.f};

    int oA = tid * 16;                   // dest byte in sA (8 KB total)
    long rowA = row0 + (oA >> 6);
    if (rowA >= N) rowA = N - 1;         // clamp tail loads (dup reads, safe)
    int kel = (oA & 63) >> 1;            // element offset in 32-elem k-chunk
    long aBase = rowA * (long)lda + kel;

    for (int k0 = 0; k0 < KI; k0 += 32) {
        f32x4 fa0, fa1;
        if constexpr (CVT) {             // reg-stage f32 A (load before barrier)
            const float* src = Af + aBase + k0;
            fa0 = *(const f32x4*)src;
            fa1 = *(const f32x4*)(src + 4);
        }
        __syncthreads();                 // prev compute done reading LDS
        if constexpr (CVT) {
            __hip_bfloat16 t8[8];
            t8[0] = __float2bfloat16(fa0[0]); t8[1] = __float2bfloat16(fa0[1]);
            t8[2] = __float2bfloat16(fa0[2]); t8[3] = __float2bfloat16(fa0[3]);
            t8[4] = __float2bfloat16(fa1[0]); t8[5] = __float2bfloat16(fa1[1]);
            t8[6] = __float2bfloat16(fa1[2]); t8[7] = __float2bfloat16(fa1[3]);
            *(bf16x8*)((char*)sA + oA) = *(const bf16x8*)t8;
        } else {
            gload_lds16(Ab + aBase + k0, (char*)sA + oA);
        }
        #pragma unroll
        for (int j = 0; j < BN / 128; ++j) {
            int o = j * 8192 + tid * 16;
            const __hip_bfloat16* src = Bt + (long)(o >> 6) * KI + k0 + ((o & 63) >> 1);
            gload_lds16(src, (char*)sB + o);
        }
        __syncthreads();                 // drains lgkm+vm before compute

        bf16x8 af[MR], bfr[4];
        #pragma unroll
        for (int mi = 0; mi < MR; ++mi)
            af[mi] = *(const bf16x8*)((const char*)sA + ((wr + mi * 16 + m) << 6) + q * 16);
        #pragma unroll
        for (int t = 0; t < 4; ++t)
            bfr[t] = *(const bf16x8*)((const char*)sB + ((wc + t * 16 + m) << 6) + q * 16);
        #pragma unroll
        for (int mi = 0; mi < MR; ++mi)
            #pragma unroll
            for (int t = 0; t < 4; ++t)
                acc[mi][t] = __builtin_amdgcn_mfma_f32_16x16x32_bf16(af[mi], bfr[t],
                                                                     acc[mi][t], 0, 0, 0);
    }

    if constexpr (MODE != 2) {
        #pragma unroll
        for (int mi = 0; mi < MR; ++mi) {
            #pragma unroll
            for (int t = 0; t < 4; ++t) {
                int col = wc + t * 16 + m;
                float bv = bias ? bias[col] : 0.f;
                #pragma unroll
                for (int r = 0; r < 4; ++r) {
                    long row = row0 + wr + mi * 16 + q * 4 + r;
                    if (row < N) {
                        float v = acc[mi][t][r] + bv;
                        if (doRelu) v = fmaxf(v, 0.f);
                        outB[row * BN + col] = __float2bfloat16(v);
                    }
                }
            }
        }
    }

    if constexpr (MODE == 1) {
        // fused attention scores: wave's 64 cols = (dir, head); reduce over 16 m-lanes.
        int dir = wc >> 8;               // BN=512: 0 or 1
        int cc = wc & 255;               // channel within dir
        int h = cc >> 6;
        const float* as_ = dir ? asrc1 : asrc0;
        const float* ad_ = dir ? adst1 : adst0;
        float* aS = dir ? aS1 : aS0;
        float* aD = dir ? aD1 : aD0;
        f32x4 sw, dw;
        #pragma unroll
        for (int t = 0; t < 4; ++t) {
            sw[t] = as_[cc + t * 16 + m];
            dw[t] = ad_[cc + t * 16 + m];
        }
        #pragma unroll
        for (int mi = 0; mi < MR; ++mi) {
            #pragma unroll
            for (int r = 0; r < 4; ++r) {
                float ps = acc[mi][0][r] * sw[0] + acc[mi][1][r] * sw[1]
                         + acc[mi][2][r] * sw[2] + acc[mi][3][r] * sw[3];
                float pd = acc[mi][0][r] * dw[0] + acc[mi][1][r] * dw[1]
                         + acc[mi][2][r] * dw[2] + acc[mi][3][r] * dw[3];
                ps = red16(ps); pd = red16(pd);
                long row = row0 + wr + mi * 16 + q * 4 + r;
                if (m == 0 && row < N) {
                    aS[row * 4 + h] = ps;
                    aD[row * 4 + h] = pd;
                }
            }
        }
    }

    if constexpr (MODE == 2) {
        // fused +bias -> LN(128) -> L2norm -> f32 out. Block covers full 128-col rows.
        float vv[MR][4][4];
        float gcol[4], bcol[4];
        #pragma unroll
        for (int t = 0; t < 4; ++t) {
            int col = wc + t * 16 + m;
            float bb = bias[col];
            gcol[t] = gw[col]; bcol[t] = bw[col];
            #pragma unroll
            for (int mi = 0; mi < MR; ++mi)
                #pragma unroll
                for (int r = 0; r < 4; ++r) vv[mi][t][r] = acc[mi][t][r] + bb;
        }
        int wcid = wc >> 6;
        #pragma unroll
        for (int mi = 0; mi < MR; ++mi) {
            #pragma unroll
            for (int r = 0; r < 4; ++r) {
                float s1 = vv[mi][0][r] + vv[mi][1][r] + vv[mi][2][r] + vv[mi][3][r];
                float s2 = vv[mi][0][r] * vv[mi][0][r] + vv[mi][1][r] * vv[mi][1][r]
                         + vv[mi][2][r] * vv[mi][2][r] + vv[mi][3][r] * vv[mi][3][r];
                s1 = red16(s1); s2 = red16(s2);
                if (m == 0) {
                    int lrow = wr + mi * 16 + q * 4 + r;
                    sRed[lrow * 4 + wcid * 2 + 0] = s1;
                    sRed[lrow * 4 + wcid * 2 + 1] = s2;
                }
            }
        }
        __syncthreads();
        #pragma unroll
        for (int mi = 0; mi < MR; ++mi) {
            #pragma unroll
            for (int r = 0; r < 4; ++r) {
                int lrow = wr + mi * 16 + q * 4 + r;
                float S1 = sRed[lrow * 4 + 0] + sRed[lrow * 4 + 2];
                float S2 = sRed[lrow * 4 + 1] + sRed[lrow * 4 + 3];
                float mean = S1 * (1.f / 128.f);
                float var = S2 * (1.f / 128.f) - mean * mean;
                float inv = rsqrtf(fmaxf(var, 0.f) + 1e-5f);
                float n2 = 0.f;
                #pragma unroll
                for (int t = 0; t < 4; ++t) {
                    float y = (vv[mi][t][r] - mean) * inv * gcol[t] + bcol[t];
                    vv[mi][t][r] = y;
                    n2 += y * y;
                }
                n2 = red16(n2);
                if (m == 0) sN2[lrow * 2 + wcid] = n2;
            }
        }
        __syncthreads();
        #pragma unroll
        for (int mi = 0; mi < MR; ++mi) {
            #pragma unroll
            for (int r = 0; r < 4; ++r) {
                int lrow = wr + mi * 16 + q * 4 + r;
                long row = row0 + lrow;
                float nrm = sqrtf(sN2[lrow * 2] + sN2[lrow * 2 + 1]);
                float sc = 1.f / fmaxf(nrm, 1e-12f);
                if (row < N) {
                    #pragma unroll
                    for (int t = 0; t < 4; ++t)
                        outF[row * 128 + wc + t * 16 + m] = vv[mi][t][r] * sc;
                }
            }
        }
    }
}

// ---------------- CSR build ----------------
__global__ __launch_bounds__(256) void hist_dst(const int* __restrict__ ei, int E,
                                                int* __restrict__ cnt) {
    int e = blockIdx.x * 256 + threadIdx.x;
    if (e < E) atomicAdd(&cnt[ei[E + e]], 1);
}

__global__ __launch_bounds__(256) void scan1(const int* __restrict__ cnt,
                                             int* __restrict__ offpart,
                                             int* __restrict__ bsum, int n) {
    int t = threadIdx.x, i = blockIdx.x * 256 + t;
    int lane = t & 63, w = t >> 6;
    int v = (i < n) ? cnt[i] : 0;
    int inc = v;
    #pragma unroll
    for (int o = 1; o < 64; o <<= 1) {
        int u = __shfl_up(inc, o, 64);
        if (lane >= o) inc += u;
    }
    __shared__ int wsum[4];
    if (lane == 63) wsum[w] = inc;
    __syncthreads();
    int wadd = 0;
    #pragma unroll
    for (int k = 0; k < 4; ++k) if (k < w) wadd += wsum[k];
    if (i < n) offpart[i] = inc - v + wadd;
    if (t == 255) bsum[blockIdx.x] = inc + wadd;
}

__global__ __launch_bounds__(256) void scan2(const int* __restrict__ bsum,
                                             int* __restrict__ btot, int nb) {
    int t = threadIdx.x, lane = t & 63, w = t >> 6;
    int loc[4]; int s = 0;
    #pragma unroll
    for (int k = 0; k < 4; ++k) {
        int idx = t * 4 + k;
        int v = (idx < nb) ? bsum[idx] : 0;
        loc[k] = s; s += v;
    }
    int inc = s;
    #pragma unroll
    for (int o = 1; o < 64; o <<= 1) {
        int u = __shfl_up(inc, o, 64);
        if (lane >= o) inc += u;
    }
    __shared__ int wsum[4];
    if (lane == 63) wsum[w] = inc;
    __syncthreads();
    int wadd = 0;
    #pragma unroll
    for (int k = 0; k < 4; ++k) if (k < w) wadd += wsum[k];
    int excl = inc - s + wadd;
    #pragma unroll
    for (int k = 0; k < 4; ++k) {
        int idx = t * 4 + k;
        if (idx < nb) btot[idx] = excl + loc[k];
    }
}

__global__ __launch_bounds__(256) void finalize_off(const int* __restrict__ offpart,
                                                    const int* __restrict__ btot,
                                                    int* __restrict__ off, int n, int E) {
    int i = blockIdx.x * 256 + threadIdx.x;
    if (i < n) off[i] = offpart[i] + btot[i >> 8];
    if (i == 0) off[n] = E;
}

__global__ __launch_bounds__(256) void scatter_src(const int* __restrict__ ei, int E,
                                                   const int* __restrict__ off,
                                                   int* __restrict__ cur,
                                                   int* __restrict__ esrc) {
    int e = blockIdx.x * 256 + threadIdx.x;
    if (e >= E) return;
    int d = ei[E + e];
    int pos = off[d] + atomicAdd(&cur[d], 1);
    esrc[pos] = ei[e];
}

// ---------------- per-dst softmax -> alpha (thread per node; avg degree ~1) ----------------
__global__ __launch_bounds__(256) void att_alpha(
    const int* __restrict__ off, const int* __restrict__ esrc,
    const float* __restrict__ a_s, const float* __restrict__ a_d,
    float* __restrict__ alpha_self, float* __restrict__ alpha_e, int N) {
    int d = blockIdx.x * 256 + threadIdx.x;
    if (d >= N) return;
    int beg = off[d], end = off[d + 1];
    f32x4 adv = *(const f32x4*)(a_d + 4 * (long)d);
    f32x4 asd = *(const f32x4*)(a_s + 4 * (long)d);
    float es[4], m[4];
    #pragma unroll
    for (int h = 0; h < 4; ++h) {
        float e = asd[h] + adv[h]; e = e > 0.f ? e : 0.2f * e;
        es[h] = e; m[h] = e;
    }
    for (int j = beg; j < end; ++j) {
        int s = esrc[j];
        f32x4 asv = *(const f32x4*)(a_s + 4 * (long)s);
        #pragma unroll
        for (int h = 0; h < 4; ++h) {
            float e = asv[h] + adv[h]; e = e > 0.f ? e : 0.2f * e;
            m[h] = fmaxf(m[h], e);
        }
    }
    float sum[4];
    #pragma unroll
    for (int h = 0; h < 4; ++h) sum[h] = __expf(es[h] - m[h]);
    for (int j = beg; j < end; ++j) {
        int s = esrc[j];
        f32x4 asv = *(const f32x4*)(a_s + 4 * (long)s);
        #pragma unroll
        for (int h = 0; h < 4; ++h) {
            float e = asv[h] + adv[h]; e = e > 0.f ? e : 0.2f * e;
            sum[h] += __expf(e - m[h]);
        }
    }
    float rs[4];
    #pragma unroll
    for (int h = 0; h < 4; ++h) rs[h] = 1.f / sum[h];
    f32x4 sa;
    #pragma unroll
    for (int h = 0; h < 4; ++h) sa[h] = __expf(es[h] - m[h]) * rs[h];
    *(f32x4*)(alpha_self + 4 * (long)d) = sa;
    for (int j = beg; j < end; ++j) {
        int s = esrc[j];
        f32x4 asv = *(const f32x4*)(a_s + 4 * (long)s);
        f32x4 av;
        #pragma unroll
        for (int h = 0; h < 4; ++h) {
            float e = asv[h] + adv[h]; e = e > 0.f ? e : 0.2f * e;
            av[h] = __expf(e - m[h]) * rs[h];
        }
        *(f32x4*)(alpha_e + 4 * (long)j) = av;
    }
}

// ---------------- gather + bias + LN + relu: 4 nodes/wave, 16 lanes x 16ch ----------------
// hw/out are [N,512] (two dirs concatenated); dirOff selects the 256-ch half.
__global__ __launch_bounds__(256) void gat_gather(
    const int* __restrict__ off, const int* __restrict__ esrc,
    const float* __restrict__ alpha_self, const float* __restrict__ alpha_e,
    const __hip_bfloat16* __restrict__ hw, int dirOff,
    const float* __restrict__ bias, const float* __restrict__ g,
    const float* __restrict__ b,
    __hip_bfloat16* __restrict__ out, int N) {
    int tid = threadIdx.x;
    int lane = tid & 63;
    int grp = lane >> 4, li = lane & 15;
    long d = (long)blockIdx.x * 16 + (tid >> 6) * 4 + grp;
    if (d >= N) return;
    int beg = off[d], end = off[d + 1];
    int head = li >> 2;          // 16 ch/lane -> single head per lane
    int c0 = li * 16;
    float acc[16];
    {   // self loop
        float a = alpha_self[4 * d + head];
        const __hip_bfloat16* r = hw + d * 512 + dirOff + c0;
        bf16x8 h0 = *(const bf16x8*)r;
        bf16x8 h1 = *(const bf16x8*)(r + 8);
        #pragma unroll
        for (int k = 0; k < 8; ++k) {
            acc[k] = a * bf2f(h0[k]);
            acc[8 + k] = a * bf2f(h1[k]);
        }
    }
    for (int j = beg; j < end; ++j) {
        int s = esrc[j];                        // uniform within group
        float a = alpha_e[4 * (long)j + head];
        const __hip_bfloat16* r = hw + (long)s * 512 + dirOff + c0;
        bf16x8 h0 = *(const bf16x8*)r;
        bf16x8 h1 = *(const bf16x8*)(r + 8);
        #pragma unroll
        for (int k = 0; k < 8; ++k) {
            acc[k] += a * bf2f(h0[k]);
            acc[8 + k] += a * bf2f(h1[k]);
        }
    }
    // bias + LN(256) within 16-lane group + relu
    float s1 = 0.f, s2 = 0.f;
    #pragma unroll
    for (int k = 0; k < 16; k += 4) {
        f32x4 bi = *(const f32x4*)(bias + c0 + k);
        #pragma unroll
        for (int u = 0; u < 4; ++u) {
            float v = acc[k + u] + bi[u];
            acc[k + u] = v;
            s1 += v; s2 += v * v;
        }
    }
    #pragma unroll
    for (int o = 1; o < 16; o <<= 1) {
        s1 += __shfl_xor(s1, o, 64);
        s2 += __shfl_xor(s2, o, 64);
    }
    float mean = s1 * (1.f / 256.f);
    float var = s2 * (1.f / 256.f) - mean * mean;
    float inv = rsqrtf(fmaxf(var, 0.f) + 1e-5f);
    __hip_bfloat16 o16[16];
    #pragma unroll
    for (int k = 0; k < 16; k += 4) {
        f32x4 gv = *(const f32x4*)(g + c0 + k);
        f32x4 bv = *(const f32x4*)(b + c0 + k);
        #pragma unroll
        for (int u = 0; u < 4; ++u) {
            float y = (acc[k + u] - mean) * inv * gv[u] + bv[u];
            o16[k + u] = __float2bfloat16(fmaxf(y, 0.f));
        }
    }
    __hip_bfloat16* orow = out + d * 512 + dirOff + c0;
    *(bf16x8*)orow = *(const bf16x8*)o16;
    *(bf16x8*)(orow + 8) = *(const bf16x8*)(o16 + 8);
}

extern "C" void kernel_launch(void* const* d_in, const int* in_sizes, int n_in,
                              void* d_out, int out_size, void* d_ws, size_t ws_size,
                              hipStream_t stream) {
    const float* x      = (const float*)d_in[0];
    const int*   ei_bu  = (const int*)d_in[1];
    const int*   ei_td  = (const int*)d_in[2];
    const float* Wp     = (const float*)d_in[3];
    const float* bp     = (const float*)d_in[4];
    const float* W_bu   = (const float*)d_in[5];
    const float* asrc_bu= (const float*)d_in[6];
    const float* adst_bu= (const float*)d_in[7];
    const float* bias_bu= (const float*)d_in[8];
    const float* W_td   = (const float*)d_in[9];
    const float* asrc_td= (const float*)d_in[10];
    const float* adst_td= (const float*)d_in[11];
    const float* bias_td= (const float*)d_in[12];
    const float* Wf     = (const float*)d_in[13];
    const float* bfv    = (const float*)d_in[14];
    const float* g_bu   = (const float*)d_in[15];
    const float* b_bu   = (const float*)d_in[16];
    const float* g_td   = (const float*)d_in[17];
    const float* b_td   = (const float*)d_in[18];
    const float* g_out  = (const float*)d_in[19];
    const float* b_out  = (const float*)d_in[20];

    const int N = in_sizes[0] / HID;   // 200000
    const int E = in_sizes[1] / 2;     // 200000

    char* ws = (char*)d_ws;
    size_t off0 = 0;
    auto take = [&](size_t bytes) -> char* {
        char* p = ws + off0;
        off0 += (bytes + 255) & ~(size_t)255;
        return p;
    };
    __hip_bfloat16* h_buf = (__hip_bfloat16*)take((size_t)N * 256 * 2);
    __hip_bfloat16* hwcat = (__hip_bfloat16*)take((size_t)N * 512 * 2); // [N][bu|td]
    __hip_bfloat16* xcat  = (__hip_bfloat16*)take((size_t)N * 512 * 2); // [N][xbu|xtd]
    float* aS0   = (float*)take((size_t)N * 16);
    float* aD0   = (float*)take((size_t)N * 16);
    float* aS1   = (float*)take((size_t)N * 16);
    float* aD1   = (float*)take((size_t)N * 16);
    float* alsf  = (float*)take((size_t)N * 16);        // alpha_self [N][4]
    float* ale   = (float*)take((size_t)E * 16);        // alpha_e [E][4] (CSR order)
    int* cnt     = (int*)take((size_t)N * 4);   // cnt and cur adjacent -> one memset
    int* cur     = (int*)take((size_t)N * 4);
    int* offpart = (int*)take((size_t)N * 4);
    int* offarr  = (int*)take((size_t)(N + 1) * 4);
    int* esrc    = (int*)take((size_t)E * 4);
    int* bsum    = (int*)take(1024 * 4);
    int* btot    = (int*)take(1024 * 4);
    __hip_bfloat16* Wpt  = (__hip_bfloat16*)take(256 * 256 * 2);
    __hip_bfloat16* Wcat = (__hip_bfloat16*)take(512 * 256 * 2);  // [512 KO][256 KI]
    __hip_bfloat16* Wft  = (__hip_bfloat16*)take(128 * 512 * 2);  // [128 KO][512 KI]

    transpose_w<<<(256 * 256 + 255) / 256, 256, 0, stream>>>(Wp, Wpt, 256, 256);
    transpose_w<<<(256 * 256 + 255) / 256, 256, 0, stream>>>(W_bu, Wcat, 256, 256);
    transpose_w<<<(256 * 256 + 255) / 256, 256, 0, stream>>>(W_td, Wcat + 256 * 256, 256, 256);
    transpose_w<<<(512 * 128 + 255) / 256, 256, 0, stream>>>(Wf, Wft, 512, 128);

    int gm = (N + 127) / 128;

    // h = relu(x @ Wp + bp)  (A staged from f32 with in-register cvt)
    gemm_tiled<256, 0, 1><<<gm, 512, 0, stream>>>(
        x, nullptr, 256, Wpt, 256, bp, 1, h_buf, nullptr,
        nullptr, nullptr, nullptr, nullptr, nullptr, nullptr, nullptr, nullptr,
        nullptr, nullptr, N);

    // hwcat = h @ [W_bu|W_td]  + fused a_src/a_dst scores for both dirs
    gemm_tiled<512, 1, 0><<<gm, 512, 0, stream>>>(
        nullptr, h_buf, 256, Wcat, 256, nullptr, 0, hwcat, nullptr,
        asrc_bu, adst_bu, asrc_td, adst_td, aS0, aD0, aS1, aD1,
        nullptr, nullptr, N);

    const int* eis[2] = {ei_bu, ei_td};
    const float* aSs[2] = {aS0, aS1};
    const float* aDs[2] = {aD0, aD1};
    const float* biases[2]= {bias_bu, bias_td};
    const float* gs[2]    = {g_bu, g_td};
    const float* bs[2]    = {b_bu, b_td};

    int egrid = (E + 255) / 256;
    int ngrid = (N + 255) / 256;
    int nb = (N + 255) / 256;
    for (int dir = 0; dir < 2; ++dir) {
        // CSR build
        hipMemsetAsync(cnt, 0, (size_t)N * 8, stream);   // cnt + cur (adjacent)
        hist_dst<<<egrid, 256, 0, stream>>>(eis[dir], E, cnt);
        scan1<<<nb, 256, 0, stream>>>(cnt, offpart, bsum, N);
        scan2<<<1, 256, 0, stream>>>(bsum, btot, nb);
        finalize_off<<<ngrid, 256, 0, stream>>>(offpart, btot, offarr, N, E);
        scatter_src<<<egrid, 256, 0, stream>>>(eis[dir], E, offarr, cur, esrc);
        // softmax (thread/node), then gather + bias + LN + relu (4 nodes/wave)
        att_alpha<<<ngrid, 256, 0, stream>>>(offarr, esrc, aSs[dir], aDs[dir],
                                             alsf, ale, N);
        gat_gather<<<(N + 15) / 16, 256, 0, stream>>>(offarr, esrc, alsf, ale,
                                                      hwcat, dir * 256,
                                                      biases[dir], gs[dir], bs[dir],
                                                      xcat, N);
    }

    // final: out = L2norm(LN(xcat @ Wf + bf)) fully fused
    gemm_tiled<128, 2, 0><<<gm, 512, 0, stream>>>(
        nullptr, xcat, 512, Wft, 512, bfv, 0, nullptr, (float*)d_out,
        nullptr, nullptr, nullptr, nullptr, nullptr, nullptr, nullptr, nullptr,
        g_out, b_out, N);
}

// Round 8
// 904.161 us; speedup vs baseline: 1.1025x; 1.0564x over previous
//
#include <hip/hip_runtime.h>
#include <hip/hip_bf16.h>
#include <stdint.h>

// HierarchicalGNN forward, FP32 in/out, MFMA bf16 GEMMs, CSR-gather GAT (no f32 atomics).
// h=relu(x@Wp+bp); two GATConv(+selfloops, softmax-per-dst) -> LN -> relu;
// concat @ Wf -> LN -> L2-normalize.
// N=200000, E=200000/dir (avg degree ~1), IN=HID=256, HEADS=4, C=64, OUT=128.
// Structure: f32->bf16 fused into GEMM1 A-staging; TWO BN=256 dir GEMMs (fused att
// scores) writing into [N,512] concat layout via ldcB/colOff; per-dir CSR + thread-
// per-node softmax + 4-nodes/wave gather; final GEMM fused bias+LN+L2norm.
// NOTE: MODE=2 requires non-null gw/bw (g_out/b_out) — passing nullptr faults (R6/R7 bug).

typedef __attribute__((ext_vector_type(8))) short bf16x8;
typedef __attribute__((ext_vector_type(4))) short bf16x4;
typedef __attribute__((ext_vector_type(4))) float f32x4;

#define HID 256

__device__ __forceinline__ float red16(float v) {   // sum within 16-lane group
    #pragma unroll
    for (int o = 1; o < 16; o <<= 1) v += __shfl_xor(v, o, 64);
    return v;
}
__device__ __forceinline__ float bf2f(short s) {
    return __uint_as_float(((unsigned)(unsigned short)s) << 16);
}

// async global->LDS, 16B per lane (global_load_lds_dwordx4).
__device__ __forceinline__ void gload_lds16(const void* g, void* l) {
    __builtin_amdgcn_global_load_lds(
        reinterpret_cast<const __attribute__((address_space(1))) uint32_t*>(
            reinterpret_cast<uintptr_t>(g)),
        reinterpret_cast<__attribute__((address_space(3))) uint32_t*>(
            reinterpret_cast<uintptr_t>(l)),
        16, 0, 0);
}

// ---------------- transpose+convert W[KI,KO] f32 -> Wt[KO,KI] bf16 ----------------
__global__ void transpose_w(const float* __restrict__ W,
                            __hip_bfloat16* __restrict__ Wt, int KI, int KO) {
    int idx = blockIdx.x * 256 + threadIdx.x;
    if (idx >= KI * KO) return;
    int k = idx / KO, j = idx % KO;
    Wt[(long)j * KI + k] = __float2bfloat16(W[idx]);
}

// ---------------- tiled MFMA GEMM: C[N,BN] = A[N,KI] @ Bt[BN,KI]^T ----------------
// BM=128, BK=32, LDS-staged; B via global_load_lds_dwordx4; A via gload (CVT=0) or
// reg-staged f32->bf16 (CVT=1). 512 threads = 8 waves.
// MODE 0: +bias/relu -> bf16 out (ldcB/colOff)
// MODE 1: bf16 out + fused a_src/a_dst scores (BN=256: wave's 64 cols = 1 head)
// MODE 2: fused +bias -> LN(128) -> L2-normalize -> f32 out (BN=128)
template<int BN, int MODE, int CVT>
__global__ __launch_bounds__(512) void gemm_tiled(
    const float* __restrict__ Af, const __hip_bfloat16* __restrict__ Ab, int lda,
    const __hip_bfloat16* __restrict__ Bt, int KI,
    const float* __restrict__ bias, int doRelu,
    __hip_bfloat16* __restrict__ outB, int ldcB, int colOff,
    float* __restrict__ outF,
    const float* __restrict__ asrcW, const float* __restrict__ adstW,
    float* __restrict__ aS, float* __restrict__ aD,
    const float* __restrict__ gw, const float* __restrict__ bw, int N) {

    constexpr int WN = BN / 64;          // waves along N (4 or 2)
    constexpr int WM = 8 / WN;           // waves along M (2 or 4)
    constexpr int MR = (128 / WM) / 16;  // m-frags per wave (4 or 2)

    __shared__ __align__(16) __hip_bfloat16 sA[128 * 32];   // [row][k] 64B rows
    __shared__ __align__(16) __hip_bfloat16 sB[BN * 32];    // [col][k] 64B rows
    __shared__ float sRed[MODE == 2 ? 128 * 4 : 4];
    __shared__ float sN2[MODE == 2 ? 128 * 2 : 2];

    int tid = threadIdx.x;
    int wv = tid >> 6, ln = tid & 63;
    int m = ln & 15, q = ln >> 4;
    long row0 = (long)blockIdx.x * 128;
    int wr = (wv / WN) * (128 / WM);
    int wc = (wv % WN) * 64;

    f32x4 acc[MR][4];
    #pragma unroll
    for (int mi = 0; mi < MR; ++mi)
        #pragma unroll
        for (int t = 0; t < 4; ++t) acc[mi][t] = (f32x4){0.f, 0.f, 0.f, 0.f};

    int oA = tid * 16;                   // dest byte in sA (8 KB total)
    long rowA = row0 + (oA >> 6);
    if (rowA >= N) rowA = N - 1;         // clamp tail loads (dup reads, safe)
    int kel = (oA & 63) >> 1;            // element offset in 32-elem k-chunk
    long aBase = rowA * (long)lda + kel;

    for (int k0 = 0; k0 < KI; k0 += 32) {
        f32x4 fa0, fa1;
        if constexpr (CVT) {             // reg-stage f32 A (load before barrier)
            const float* src = Af + aBase + k0;
            fa0 = *(const f32x4*)src;
            fa1 = *(const f32x4*)(src + 4);
        }
        __syncthreads();                 // prev compute done reading LDS
        if constexpr (CVT) {
            __hip_bfloat16 t8[8];
            t8[0] = __float2bfloat16(fa0[0]); t8[1] = __float2bfloat16(fa0[1]);
            t8[2] = __float2bfloat16(fa0[2]); t8[3] = __float2bfloat16(fa0[3]);
            t8[4] = __float2bfloat16(fa1[0]); t8[5] = __float2bfloat16(fa1[1]);
            t8[6] = __float2bfloat16(fa1[2]); t8[7] = __float2bfloat16(fa1[3]);
            *(bf16x8*)((char*)sA + oA) = *(const bf16x8*)t8;
        } else {
            gload_lds16(Ab + aBase + k0, (char*)sA + oA);
        }
        #pragma unroll
        for (int j = 0; j < BN / 128; ++j) {
            int o = j * 8192 + tid * 16;
            const __hip_bfloat16* src = Bt + (long)(o >> 6) * KI + k0 + ((o & 63) >> 1);
            gload_lds16(src, (char*)sB + o);
        }
        __syncthreads();                 // drains lgkm+vm before compute

        bf16x8 af[MR], bfr[4];
        #pragma unroll
        for (int mi = 0; mi < MR; ++mi)
            af[mi] = *(const bf16x8*)((const char*)sA + ((wr + mi * 16 + m) << 6) + q * 16);
        #pragma unroll
        for (int t = 0; t < 4; ++t)
            bfr[t] = *(const bf16x8*)((const char*)sB + ((wc + t * 16 + m) << 6) + q * 16);
        #pragma unroll
        for (int mi = 0; mi < MR; ++mi)
            #pragma unroll
            for (int t = 0; t < 4; ++t)
                acc[mi][t] = __builtin_amdgcn_mfma_f32_16x16x32_bf16(af[mi], bfr[t],
                                                                     acc[mi][t], 0, 0, 0);
    }

    if constexpr (MODE != 2) {
        #pragma unroll
        for (int mi = 0; mi < MR; ++mi) {
            #pragma unroll
            for (int t = 0; t < 4; ++t) {
                int col = wc + t * 16 + m;
                float bv = bias ? bias[col] : 0.f;
                #pragma unroll
                for (int r = 0; r < 4; ++r) {
                    long row = row0 + wr + mi * 16 + q * 4 + r;
                    if (row < N) {
                        float v = acc[mi][t][r] + bv;
                        if (doRelu) v = fmaxf(v, 0.f);
                        outB[row * ldcB + colOff + col] = __float2bfloat16(v);
                    }
                }
            }
        }
    }

    if constexpr (MODE == 1) {
        // fused attention scores: wave's 64 cols = head h; reduce over 16 m-lanes.
        int h = wc >> 6;
        f32x4 sw, dw;
        #pragma unroll
        for (int t = 0; t < 4; ++t) {
            sw[t] = asrcW[wc + t * 16 + m];
            dw[t] = adstW[wc + t * 16 + m];
        }
        #pragma unroll
        for (int mi = 0; mi < MR; ++mi) {
            #pragma unroll
            for (int r = 0; r < 4; ++r) {
                float ps = acc[mi][0][r] * sw[0] + acc[mi][1][r] * sw[1]
                         + acc[mi][2][r] * sw[2] + acc[mi][3][r] * sw[3];
                float pd = acc[mi][0][r] * dw[0] + acc[mi][1][r] * dw[1]
                         + acc[mi][2][r] * dw[2] + acc[mi][3][r] * dw[3];
                ps = red16(ps); pd = red16(pd);
                long row = row0 + wr + mi * 16 + q * 4 + r;
                if (m == 0 && row < N) {
                    aS[row * 4 + h] = ps;
                    aD[row * 4 + h] = pd;
                }
            }
        }
    }

    if constexpr (MODE == 2) {
        // fused +bias -> LN(128) -> L2norm -> f32 out. Block covers full 128-col rows.
        float vv[MR][4][4];
        float gcol[4], bcol[4];
        #pragma unroll
        for (int t = 0; t < 4; ++t) {
            int col = wc + t * 16 + m;
            float bb = bias[col];
            gcol[t] = gw[col]; bcol[t] = bw[col];
            #pragma unroll
            for (int mi = 0; mi < MR; ++mi)
                #pragma unroll
                for (int r = 0; r < 4; ++r) vv[mi][t][r] = acc[mi][t][r] + bb;
        }
        int wcid = wc >> 6;
        #pragma unroll
        for (int mi = 0; mi < MR; ++mi) {
            #pragma unroll
            for (int r = 0; r < 4; ++r) {
                float s1 = vv[mi][0][r] + vv[mi][1][r] + vv[mi][2][r] + vv[mi][3][r];
                float s2 = vv[mi][0][r] * vv[mi][0][r] + vv[mi][1][r] * vv[mi][1][r]
                         + vv[mi][2][r] * vv[mi][2][r] + vv[mi][3][r] * vv[mi][3][r];
                s1 = red16(s1); s2 = red16(s2);
                if (m == 0) {
                    int lrow = wr + mi * 16 + q * 4 + r;
                    sRed[lrow * 4 + wcid * 2 + 0] = s1;
                    sRed[lrow * 4 + wcid * 2 + 1] = s2;
                }
            }
        }
        __syncthreads();
        #pragma unroll
        for (int mi = 0; mi < MR; ++mi) {
            #pragma unroll
            for (int r = 0; r < 4; ++r) {
                int lrow = wr + mi * 16 + q * 4 + r;
                float S1 = sRed[lrow * 4 + 0] + sRed[lrow * 4 + 2];
                float S2 = sRed[lrow * 4 + 1] + sRed[lrow * 4 + 3];
                float mean = S1 * (1.f / 128.f);
                float var = S2 * (1.f / 128.f) - mean * mean;
                float inv = rsqrtf(fmaxf(var, 0.f) + 1e-5f);
                float n2 = 0.f;
                #pragma unroll
                for (int t = 0; t < 4; ++t) {
                    float y = (vv[mi][t][r] - mean) * inv * gcol[t] + bcol[t];
                    vv[mi][t][r] = y;
                    n2 += y * y;
                }
                n2 = red16(n2);
                if (m == 0) sN2[lrow * 2 + wcid] = n2;
            }
        }
        __syncthreads();
        #pragma unroll
        for (int mi = 0; mi < MR; ++mi) {
            #pragma unroll
            for (int r = 0; r < 4; ++r) {
                int lrow = wr + mi * 16 + q * 4 + r;
                long row = row0 + lrow;
                float nrm = sqrtf(sN2[lrow * 2] + sN2[lrow * 2 + 1]);
                float sc = 1.f / fmaxf(nrm, 1e-12f);
                if (row < N) {
                    #pragma unroll
                    for (int t = 0; t < 4; ++t)
                        outF[row * 128 + wc + t * 16 + m] = vv[mi][t][r] * sc;
                }
            }
        }
    }
}

// ---------------- CSR build (per dir) ----------------
__global__ __launch_bounds__(256) void hist_dst(const int* __restrict__ ei, int E,
                                                int* __restrict__ cnt) {
    int e = blockIdx.x * 256 + threadIdx.x;
    if (e < E) atomicAdd(&cnt[ei[E + e]], 1);
}

__global__ __launch_bounds__(256) void scan1(const int* __restrict__ cnt,
                                             int* __restrict__ offpart,
                                             int* __restrict__ bsum, int n) {
    int t = threadIdx.x, i = blockIdx.x * 256 + t;
    int lane = t & 63, w = t >> 6;
    int v = (i < n) ? cnt[i] : 0;
    int inc = v;
    #pragma unroll
    for (int o = 1; o < 64; o <<= 1) {
        int u = __shfl_up(inc, o, 64);
        if (lane >= o) inc += u;
    }
    __shared__ int wsum[4];
    if (lane == 63) wsum[w] = inc;
    __syncthreads();
    int wadd = 0;
    #pragma unroll
    for (int k = 0; k < 4; ++k) if (k < w) wadd += wsum[k];
    if (i < n) offpart[i] = inc - v + wadd;
    if (t == 255) bsum[blockIdx.x] = inc + wadd;
}

// exclusive scan of up to 1024 block sums, single block of 256 threads
__global__ __launch_bounds__(256) void scan2(const int* __restrict__ bsum,
                                             int* __restrict__ btot, int nb) {
    int t = threadIdx.x, lane = t & 63, w = t >> 6;
    int loc[4]; int s = 0;
    #pragma unroll
    for (int k = 0; k < 4; ++k) {
        int idx = t * 4 + k;
        int v = (idx < nb) ? bsum[idx] : 0;
        loc[k] = s; s += v;
    }
    int inc = s;
    #pragma unroll
    for (int o = 1; o < 64; o <<= 1) {
        int u = __shfl_up(inc, o, 64);
        if (lane >= o) inc += u;
    }
    __shared__ int wsum[4];
    if (lane == 63) wsum[w] = inc;
    __syncthreads();
    int wadd = 0;
    #pragma unroll
    for (int k = 0; k < 4; ++k) if (k < w) wadd += wsum[k];
    int excl = inc - s + wadd;
    #pragma unroll
    for (int k = 0; k < 4; ++k) {
        int idx = t * 4 + k;
        if (idx < nb) btot[idx] = excl + loc[k];
    }
}

__global__ __launch_bounds__(256) void finalize_off(const int* __restrict__ offpart,
                                                    const int* __restrict__ btot,
                                                    int* __restrict__ off, int n, int E) {
    int i = blockIdx.x * 256 + threadIdx.x;
    if (i < n) off[i] = offpart[i] + btot[i >> 8];
    if (i == 0) off[n] = E;
}

__global__ __launch_bounds__(256) void scatter_src(const int* __restrict__ ei, int E,
                                                   const int* __restrict__ off,
                                                   int* __restrict__ cur,
                                                   int* __restrict__ esrc) {
    int e = blockIdx.x * 256 + threadIdx.x;
    if (e >= E) return;
    int d = ei[E + e];
    int pos = off[d] + atomicAdd(&cur[d], 1);
    esrc[pos] = ei[e];
}

// ---------------- per-dst softmax -> alpha (thread per node; avg degree ~1) ----------------
__global__ __launch_bounds__(256) void att_alpha(
    const int* __restrict__ off, const int* __restrict__ esrc,
    const float* __restrict__ a_s, const float* __restrict__ a_d,
    float* __restrict__ alpha_self, float* __restrict__ alpha_e, int N) {
    int d = blockIdx.x * 256 + threadIdx.x;
    if (d >= N) return;
    int beg = off[d], end = off[d + 1];
    f32x4 adv = *(const f32x4*)(a_d + 4 * (long)d);
    f32x4 asd = *(const f32x4*)(a_s + 4 * (long)d);
    float es[4], m[4];
    #pragma unroll
    for (int h = 0; h < 4; ++h) {
        float e = asd[h] + adv[h]; e = e > 0.f ? e : 0.2f * e;
        es[h] = e; m[h] = e;
    }
    for (int j = beg; j < end; ++j) {
        int s = esrc[j];
        f32x4 asv = *(const f32x4*)(a_s + 4 * (long)s);
        #pragma unroll
        for (int h = 0; h < 4; ++h) {
            float e = asv[h] + adv[h]; e = e > 0.f ? e : 0.2f * e;
            m[h] = fmaxf(m[h], e);
        }
    }
    float sum[4];
    #pragma unroll
    for (int h = 0; h < 4; ++h) sum[h] = __expf(es[h] - m[h]);
    for (int j = beg; j < end; ++j) {
        int s = esrc[j];
        f32x4 asv = *(const f32x4*)(a_s + 4 * (long)s);
        #pragma unroll
        for (int h = 0; h < 4; ++h) {
            float e = asv[h] + adv[h]; e = e > 0.f ? e : 0.2f * e;
            sum[h] += __expf(e - m[h]);
        }
    }
    float rs[4];
    #pragma unroll
    for (int h = 0; h < 4; ++h) rs[h] = 1.f / sum[h];
    f32x4 sa;
    #pragma unroll
    for (int h = 0; h < 4; ++h) sa[h] = __expf(es[h] - m[h]) * rs[h];
    *(f32x4*)(alpha_self + 4 * (long)d) = sa;
    for (int j = beg; j < end; ++j) {
        int s = esrc[j];
        f32x4 asv = *(const f32x4*)(a_s + 4 * (long)s);
        f32x4 av;
        #pragma unroll
        for (int h = 0; h < 4; ++h) {
            float e = asv[h] + adv[h]; e = e > 0.f ? e : 0.2f * e;
            av[h] = __expf(e - m[h]) * rs[h];
        }
        *(f32x4*)(alpha_e + 4 * (long)j) = av;
    }
}

// ---------------- gather + bias + LN + relu: 4 nodes/wave, 16 lanes x 16ch ----------------
// hw/out are [N,512] (two dirs concatenated); dirOff selects the 256-ch half.
__global__ __launch_bounds__(256) void gat_gather(
    const int* __restrict__ off, const int* __restrict__ esrc,
    const float* __restrict__ alpha_self, const float* __restrict__ alpha_e,
    const __hip_bfloat16* __restrict__ hw, int dirOff,
    const float* __restrict__ bias, const float* __restrict__ g,
    const float* __restrict__ b,
    __hip_bfloat16* __restrict__ out, int N) {
    int tid = threadIdx.x;
    int lane = tid & 63;
    int grp = lane >> 4, li = lane & 15;
    long d = (long)blockIdx.x * 16 + (tid >> 6) * 4 + grp;
    if (d >= N) return;
    int beg = off[d], end = off[d + 1];
    int head = li >> 2;          // 16 ch/lane -> single head per lane
    int c0 = li * 16;
    float acc[16];
    {   // self loop
        float a = alpha_self[4 * d + head];
        const __hip_bfloat16* r = hw + d * 512 + dirOff + c0;
        bf16x8 h0 = *(const bf16x8*)r;
        bf16x8 h1 = *(const bf16x8*)(r + 8);
        #pragma unroll
        for (int k = 0; k < 8; ++k) {
            acc[k] = a * bf2f(h0[k]);
            acc[8 + k] = a * bf2f(h1[k]);
        }
    }
    for (int j = beg; j < end; ++j) {
        int s = esrc[j];                        // uniform within group
        float a = alpha_e[4 * (long)j + head];
        const __hip_bfloat16* r = hw + (long)s * 512 + dirOff + c0;
        bf16x8 h0 = *(const bf16x8*)r;
        bf16x8 h1 = *(const bf16x8*)(r + 8);
        #pragma unroll
        for (int k = 0; k < 8; ++k) {
            acc[k] += a * bf2f(h0[k]);
            acc[8 + k] += a * bf2f(h1[k]);
        }
    }
    // bias + LN(256) within 16-lane group + relu
    float s1 = 0.f, s2 = 0.f;
    #pragma unroll
    for (int k = 0; k < 16; k += 4) {
        f32x4 bi = *(const f32x4*)(bias + c0 + k);
        #pragma unroll
        for (int u = 0; u < 4; ++u) {
            float v = acc[k + u] + bi[u];
            acc[k + u] = v;
            s1 += v; s2 += v * v;
        }
    }
    #pragma unroll
    for (int o = 1; o < 16; o <<= 1) {
        s1 += __shfl_xor(s1, o, 64);
        s2 += __shfl_xor(s2, o, 64);
    }
    float mean = s1 * (1.f / 256.f);
    float var = s2 * (1.f / 256.f) - mean * mean;
    float inv = rsqrtf(fmaxf(var, 0.f) + 1e-5f);
    __hip_bfloat16 o16[16];
    #pragma unroll
    for (int k = 0; k < 16; k += 4) {
        f32x4 gv = *(const f32x4*)(g + c0 + k);
        f32x4 bv = *(const f32x4*)(b + c0 + k);
        #pragma unroll
        for (int u = 0; u < 4; ++u) {
            float y = (acc[k + u] - mean) * inv * gv[u] + bv[u];
            o16[k + u] = __float2bfloat16(fmaxf(y, 0.f));
        }
    }
    __hip_bfloat16* orow = out + d * 512 + dirOff + c0;
    *(bf16x8*)orow = *(const bf16x8*)o16;
    *(bf16x8*)(orow + 8) = *(const bf16x8*)(o16 + 8);
}

extern "C" void kernel_launch(void* const* d_in, const int* in_sizes, int n_in,
                              void* d_out, int out_size, void* d_ws, size_t ws_size,
                              hipStream_t stream) {
    const float* x      = (const float*)d_in[0];
    const int*   ei_bu  = (const int*)d_in[1];
    const int*   ei_td  = (const int*)d_in[2];
    const float* Wp     = (const float*)d_in[3];
    const float* bp     = (const float*)d_in[4];
    const float* W_bu   = (const float*)d_in[5];
    const float* asrc_bu= (const float*)d_in[6];
    const float* adst_bu= (const float*)d_in[7];
    const float* bias_bu= (const float*)d_in[8];
    const float* W_td   = (const float*)d_in[9];
    const float* asrc_td= (const float*)d_in[10];
    const float* adst_td= (const float*)d_in[11];
    const float* bias_td= (const float*)d_in[12];
    const float* Wf     = (const float*)d_in[13];
    const float* bfv    = (const float*)d_in[14];
    const float* g_bu   = (const float*)d_in[15];
    const float* b_bu   = (const float*)d_in[16];
    const float* g_td   = (const float*)d_in[17];
    const float* b_td   = (const float*)d_in[18];
    const float* g_out  = (const float*)d_in[19];
    const float* b_out  = (const float*)d_in[20];

    const int N = in_sizes[0] / HID;   // 200000
    const int E = in_sizes[1] / 2;     // 200000

    char* ws = (char*)d_ws;
    size_t off0 = 0;
    auto take = [&](size_t bytes) -> char* {
        char* p = ws + off0;
        off0 += (bytes + 255) & ~(size_t)255;
        return p;
    };
    __hip_bfloat16* h_buf = (__hip_bfloat16*)take((size_t)N * 256 * 2);
    __hip_bfloat16* hwcat = (__hip_bfloat16*)take((size_t)N * 512 * 2); // [N][bu|td]
    __hip_bfloat16* xcat  = (__hip_bfloat16*)take((size_t)N * 512 * 2); // [N][xbu|xtd]
    float* aS0   = (float*)take((size_t)N * 16);
    float* aD0   = (float*)take((size_t)N * 16);
    float* aS1   = (float*)take((size_t)N * 16);
    float* aD1   = (float*)take((size_t)N * 16);
    float* alsf  = (float*)take((size_t)N * 16);        // alpha_self [N][4]
    float* ale   = (float*)take((size_t)E * 16);        // alpha_e [E][4] (CSR order)
    int* cnt     = (int*)take((size_t)N * 4);   // cnt and cur adjacent -> one memset
    int* cur     = (int*)take((size_t)N * 4);
    int* offpart = (int*)take((size_t)N * 4);
    int* offarr  = (int*)take((size_t)(N + 1) * 4);
    int* esrc    = (int*)take((size_t)E * 4);
    int* bsum    = (int*)take(1024 * 4);
    int* btot    = (int*)take(1024 * 4);
    __hip_bfloat16* Wpt  = (__hip_bfloat16*)take(256 * 256 * 2);
    __hip_bfloat16* Wcat = (__hip_bfloat16*)take(512 * 256 * 2);  // [512 KO][256 KI]
    __hip_bfloat16* Wft  = (__hip_bfloat16*)take(128 * 512 * 2);  // [128 KO][512 KI]

    transpose_w<<<(256 * 256 + 255) / 256, 256, 0, stream>>>(Wp, Wpt, 256, 256);
    transpose_w<<<(256 * 256 + 255) / 256, 256, 0, stream>>>(W_bu, Wcat, 256, 256);
    transpose_w<<<(256 * 256 + 255) / 256, 256, 0, stream>>>(W_td, Wcat + 256 * 256, 256, 256);
    transpose_w<<<(512 * 128 + 255) / 256, 256, 0, stream>>>(Wf, Wft, 512, 128);

    int gm = (N + 127) / 128;

    // h = relu(x @ Wp + bp)  (A staged from f32 with in-register cvt)
    gemm_tiled<256, 0, 1><<<gm, 512, 0, stream>>>(
        x, nullptr, 256, Wpt, 256, bp, 1, h_buf, 256, 0, nullptr,
        nullptr, nullptr, nullptr, nullptr, nullptr, nullptr, N);

    // hwcat[:, dir*256..] = h @ W_dir  + fused a_src/a_dst scores
    gemm_tiled<256, 1, 0><<<gm, 512, 0, stream>>>(
        nullptr, h_buf, 256, Wcat, 256, nullptr, 0, hwcat, 512, 0, nullptr,
        asrc_bu, adst_bu, aS0, aD0, nullptr, nullptr, N);
    gemm_tiled<256, 1, 0><<<gm, 512, 0, stream>>>(
        nullptr, h_buf, 256, Wcat + 256 * 256, 256, nullptr, 0, hwcat, 512, 256, nullptr,
        asrc_td, adst_td, aS1, aD1, nullptr, nullptr, N);

    const int* eis[2] = {ei_bu, ei_td};
    const float* aSs[2] = {aS0, aS1};
    const float* aDs[2] = {aD0, aD1};
    const float* biases[2]= {bias_bu, bias_td};
    const float* gs[2]    = {g_bu, g_td};
    const float* bs[2]    = {b_bu, b_td};

    int egrid = (E + 255) / 256;
    int ngrid = (N + 255) / 256;
    int nb = (N + 255) / 256;
    for (int dir = 0; dir < 2; ++dir) {
        // CSR build
        hipMemsetAsync(cnt, 0, (size_t)N * 8, stream);   // cnt + cur (adjacent)
        hist_dst<<<egrid, 256, 0, stream>>>(eis[dir], E, cnt);
        scan1<<<nb, 256, 0, stream>>>(cnt, offpart, bsum, N);
        scan2<<<1, 256, 0, stream>>>(bsum, btot, nb);
        finalize_off<<<ngrid, 256, 0, stream>>>(offpart, btot, offarr, N, E);
        scatter_src<<<egrid, 256, 0, stream>>>(eis[dir], E, offarr, cur, esrc);
        // softmax (thread/node), then gather + bias + LN + relu (4 nodes/wave)
        att_alpha<<<ngrid, 256, 0, stream>>>(offarr, esrc, aSs[dir], aDs[dir],
                                             alsf, ale, N);
        gat_gather<<<(N + 15) / 16, 256, 0, stream>>>(offarr, esrc, alsf, ale,
                                                      hwcat, dir * 256,
                                                      biases[dir], gs[dir], bs[dir],
                                                      xcat, N);
    }

    // final: out = L2norm(LN(xcat @ Wf + bf)) fully fused  (gw/bw MUST be non-null)
    gemm_tiled<128, 2, 0><<<gm, 512, 0, stream>>>(
        nullptr, xcat, 512, Wft, 512, bfv, 0, nullptr, 128, 0, (float*)d_out,
        nullptr, nullptr, nullptr, nullptr, g_out, b_out, N);
}

// Round 9
// 892.747 us; speedup vs baseline: 1.1166x; 1.0128x over previous
//
#include <hip/hip_runtime.h>
#include <hip/hip_bf16.h>
#include <stdint.h>

// HierarchicalGNN forward, FP32 in/out, MFMA bf16 GEMMs, CSR-gather GAT (no f32 atomics).
// h=relu(x@Wp+bp); two GATConv(+selfloops, softmax-per-dst) -> LN -> relu;
// concat @ Wf -> LN -> L2-normalize.
// N=200000, E=200000/dir (avg degree ~1), IN=HID=256, HEADS=4, C=64, OUT=128.
// Structure: f32->bf16 fused into GEMM1 A-staging; TWO BN=256 dir GEMMs (fused att
// scores) writing into [N,512] concat layout; per-dir CSR + thread-per-node softmax +
// 4-nodes/wave gather; final GEMM fused bias+LN+L2norm.
// GEMM K-loop: double-buffered LDS, stage(k+1) issued BEFORE compute(k), one
// __syncthreads()/step (T3 minimum-2-phase recipe) — overlaps HBM latency with MFMA.
// NOTE: MODE=2 requires non-null gw/bw (g_out/b_out) — nullptr faults (R6/R7 bug).

typedef __attribute__((ext_vector_type(8))) short bf16x8;
typedef __attribute__((ext_vector_type(4))) short bf16x4;
typedef __attribute__((ext_vector_type(4))) float f32x4;

#define HID 256

__device__ __forceinline__ float red16(float v) {   // sum within 16-lane group
    #pragma unroll
    for (int o = 1; o < 16; o <<= 1) v += __shfl_xor(v, o, 64);
    return v;
}
__device__ __forceinline__ float bf2f(short s) {
    return __uint_as_float(((unsigned)(unsigned short)s) << 16);
}

// async global->LDS, 16B per lane (global_load_lds_dwordx4).
__device__ __forceinline__ void gload_lds16(const void* g, void* l) {
    __builtin_amdgcn_global_load_lds(
        reinterpret_cast<const __attribute__((address_space(1))) uint32_t*>(
            reinterpret_cast<uintptr_t>(g)),
        reinterpret_cast<__attribute__((address_space(3))) uint32_t*>(
            reinterpret_cast<uintptr_t>(l)),
        16, 0, 0);
}

// ---------------- transpose+convert W[KI,KO] f32 -> Wt[KO,KI] bf16 ----------------
__global__ void transpose_w(const float* __restrict__ W,
                            __hip_bfloat16* __restrict__ Wt, int KI, int KO) {
    int idx = blockIdx.x * 256 + threadIdx.x;
    if (idx >= KI * KO) return;
    int k = idx / KO, j = idx % KO;
    Wt[(long)j * KI + k] = __float2bfloat16(W[idx]);
}

// ---------------- tiled MFMA GEMM: C[N,BN] = A[N,KI] @ Bt[BN,KI]^T ----------------
// BM=128, BK=32, double-buffered LDS; B via global_load_lds_dwordx4; A via gload
// (CVT=0) or reg-staged f32->bf16 (CVT=1). 512 threads = 8 waves.
// MODE 0: +bias/relu -> bf16 out (ldcB/colOff)
// MODE 1: bf16 out + fused a_src/a_dst scores (BN=256: wave's 64 cols = 1 head)
// MODE 2: fused +bias -> LN(128) -> L2-normalize -> f32 out (BN=128)
template<int BN, int MODE, int CVT>
__global__ __launch_bounds__(512) void gemm_tiled(
    const float* __restrict__ Af, const __hip_bfloat16* __restrict__ Ab, int lda,
    const __hip_bfloat16* __restrict__ Bt, int KI,
    const float* __restrict__ bias, int doRelu,
    __hip_bfloat16* __restrict__ outB, int ldcB, int colOff,
    float* __restrict__ outF,
    const float* __restrict__ asrcW, const float* __restrict__ adstW,
    float* __restrict__ aS, float* __restrict__ aD,
    const float* __restrict__ gw, const float* __restrict__ bw, int N) {

    constexpr int WN = BN / 64;          // waves along N (4 or 2)
    constexpr int WM = 8 / WN;           // waves along M (2 or 4)
    constexpr int MR = (128 / WM) / 16;  // m-frags per wave (4 or 2)

    __shared__ __align__(16) __hip_bfloat16 sA[2][128 * 32];  // [buf][row][k] 64B rows
    __shared__ __align__(16) __hip_bfloat16 sB[2][BN * 32];   // [buf][col][k] 64B rows
    __shared__ float sRed[MODE == 2 ? 128 * 4 : 4];
    __shared__ float sN2[MODE == 2 ? 128 * 2 : 2];

    int tid = threadIdx.x;
    int wv = tid >> 6, ln = tid & 63;
    int m = ln & 15, q = ln >> 4;
    long row0 = (long)blockIdx.x * 128;
    int wr = (wv / WN) * (128 / WM);
    int wc = (wv % WN) * 64;

    f32x4 acc[MR][4];
    #pragma unroll
    for (int mi = 0; mi < MR; ++mi)
        #pragma unroll
        for (int t = 0; t < 4; ++t) acc[mi][t] = (f32x4){0.f, 0.f, 0.f, 0.f};

    int oA = tid * 16;                   // dest byte in sA buf (8 KB total)
    long rowA = row0 + (oA >> 6);
    if (rowA >= N) rowA = N - 1;         // clamp tail loads (dup reads, safe)
    int kel = (oA & 63) >> 1;            // element offset in 32-elem k-chunk
    long aBase = rowA * (long)lda + kel;

    // stage tile at k0 into buffer buf (issues async loads; CVT path is blocking-ish)
    auto stage = [&](int buf, int k0) {
        if constexpr (CVT) {
            const float* src = Af + aBase + k0;
            f32x4 fa0 = *(const f32x4*)src;
            f32x4 fa1 = *(const f32x4*)(src + 4);
            __hip_bfloat16 t8[8];
            t8[0] = __float2bfloat16(fa0[0]); t8[1] = __float2bfloat16(fa0[1]);
            t8[2] = __float2bfloat16(fa0[2]); t8[3] = __float2bfloat16(fa0[3]);
            t8[4] = __float2bfloat16(fa1[0]); t8[5] = __float2bfloat16(fa1[1]);
            t8[6] = __float2bfloat16(fa1[2]); t8[7] = __float2bfloat16(fa1[3]);
            *(bf16x8*)((char*)sA[buf] + oA) = *(const bf16x8*)t8;
        } else {
            gload_lds16(Ab + aBase + k0, (char*)sA[buf] + oA);
        }
        #pragma unroll
        for (int j = 0; j < BN / 128; ++j) {
            int o = j * 8192 + tid * 16;
            const __hip_bfloat16* src = Bt + (long)(o >> 6) * KI + k0 + ((o & 63) >> 1);
            gload_lds16(src, (char*)sB[buf] + o);
        }
    };

    stage(0, 0);
    __syncthreads();                     // compiler drains vmcnt(0): buf0 ready
    int cur = 0;
    for (int k0 = 0; k0 < KI; k0 += 32) {
        if (k0 + 32 < KI) stage(cur ^ 1, k0 + 32);   // loads fly under compute below

        bf16x8 af[MR], bfr[4];
        #pragma unroll
        for (int mi = 0; mi < MR; ++mi)
            af[mi] = *(const bf16x8*)((const char*)sA[cur] + ((wr + mi * 16 + m) << 6) + q * 16);
        #pragma unroll
        for (int t = 0; t < 4; ++t)
            bfr[t] = *(const bf16x8*)((const char*)sB[cur] + ((wc + t * 16 + m) << 6) + q * 16);
        #pragma unroll
        for (int mi = 0; mi < MR; ++mi)
            #pragma unroll
            for (int t = 0; t < 4; ++t)
                acc[mi][t] = __builtin_amdgcn_mfma_f32_16x16x32_bf16(af[mi], bfr[t],
                                                                     acc[mi][t], 0, 0, 0);
        __syncthreads();                 // drains next-tile loads; frees cur for k0+64
        cur ^= 1;
    }

    if constexpr (MODE != 2) {
        #pragma unroll
        for (int mi = 0; mi < MR; ++mi) {
            #pragma unroll
            for (int t = 0; t < 4; ++t) {
                int col = wc + t * 16 + m;
                float bv = bias ? bias[col] : 0.f;
                #pragma unroll
                for (int r = 0; r < 4; ++r) {
                    long row = row0 + wr + mi * 16 + q * 4 + r;
                    if (row < N) {
                        float v = acc[mi][t][r] + bv;
                        if (doRelu) v = fmaxf(v, 0.f);
                        outB[row * ldcB + colOff + col] = __float2bfloat16(v);
                    }
                }
            }
        }
    }

    if constexpr (MODE == 1) {
        // fused attention scores: wave's 64 cols = head h; reduce over 16 m-lanes.
        int h = wc >> 6;
        f32x4 sw, dw;
        #pragma unroll
        for (int t = 0; t < 4; ++t) {
            sw[t] = asrcW[wc + t * 16 + m];
            dw[t] = adstW[wc + t * 16 + m];
        }
        #pragma unroll
        for (int mi = 0; mi < MR; ++mi) {
            #pragma unroll
            for (int r = 0; r < 4; ++r) {
                float ps = acc[mi][0][r] * sw[0] + acc[mi][1][r] * sw[1]
                         + acc[mi][2][r] * sw[2] + acc[mi][3][r] * sw[3];
                float pd = acc[mi][0][r] * dw[0] + acc[mi][1][r] * dw[1]
                         + acc[mi][2][r] * dw[2] + acc[mi][3][r] * dw[3];
                ps = red16(ps); pd = red16(pd);
                long row = row0 + wr + mi * 16 + q * 4 + r;
                if (m == 0 && row < N) {
                    aS[row * 4 + h] = ps;
                    aD[row * 4 + h] = pd;
                }
            }
        }
    }

    if constexpr (MODE == 2) {
        // fused +bias -> LN(128) -> L2norm -> f32 out. Block covers full 128-col rows.
        float vv[MR][4][4];
        float gcol[4], bcol[4];
        #pragma unroll
        for (int t = 0; t < 4; ++t) {
            int col = wc + t * 16 + m;
            float bb = bias[col];
            gcol[t] = gw[col]; bcol[t] = bw[col];
            #pragma unroll
            for (int mi = 0; mi < MR; ++mi)
                #pragma unroll
                for (int r = 0; r < 4; ++r) vv[mi][t][r] = acc[mi][t][r] + bb;
        }
        int wcid = wc >> 6;
        #pragma unroll
        for (int mi = 0; mi < MR; ++mi) {
            #pragma unroll
            for (int r = 0; r < 4; ++r) {
                float s1 = vv[mi][0][r] + vv[mi][1][r] + vv[mi][2][r] + vv[mi][3][r];
                float s2 = vv[mi][0][r] * vv[mi][0][r] + vv[mi][1][r] * vv[mi][1][r]
                         + vv[mi][2][r] * vv[mi][2][r] + vv[mi][3][r] * vv[mi][3][r];
                s1 = red16(s1); s2 = red16(s2);
                if (m == 0) {
                    int lrow = wr + mi * 16 + q * 4 + r;
                    sRed[lrow * 4 + wcid * 2 + 0] = s1;
                    sRed[lrow * 4 + wcid * 2 + 1] = s2;
                }
            }
        }
        __syncthreads();
        #pragma unroll
        for (int mi = 0; mi < MR; ++mi) {
            #pragma unroll
            for (int r = 0; r < 4; ++r) {
                int lrow = wr + mi * 16 + q * 4 + r;
                float S1 = sRed[lrow * 4 + 0] + sRed[lrow * 4 + 2];
                float S2 = sRed[lrow * 4 + 1] + sRed[lrow * 4 + 3];
                float mean = S1 * (1.f / 128.f);
                float var = S2 * (1.f / 128.f) - mean * mean;
                float inv = rsqrtf(fmaxf(var, 0.f) + 1e-5f);
                float n2 = 0.f;
                #pragma unroll
                for (int t = 0; t < 4; ++t) {
                    float y = (vv[mi][t][r] - mean) * inv * gcol[t] + bcol[t];
                    vv[mi][t][r] = y;
                    n2 += y * y;
                }
                n2 = red16(n2);
                if (m == 0) sN2[lrow * 2 + wcid] = n2;
            }
        }
        __syncthreads();
        #pragma unroll
        for (int mi = 0; mi < MR; ++mi) {
            #pragma unroll
            for (int r = 0; r < 4; ++r) {
                int lrow = wr + mi * 16 + q * 4 + r;
                long row = row0 + lrow;
                float nrm = sqrtf(sN2[lrow * 2] + sN2[lrow * 2 + 1]);
                float sc = 1.f / fmaxf(nrm, 1e-12f);
                if (row < N) {
                    #pragma unroll
                    for (int t = 0; t < 4; ++t)
                        outF[row * 128 + wc + t * 16 + m] = vv[mi][t][r] * sc;
                }
            }
        }
    }
}

// ---------------- CSR build (per dir) ----------------
__global__ __launch_bounds__(256) void hist_dst(const int* __restrict__ ei, int E,
                                                int* __restrict__ cnt) {
    int e = blockIdx.x * 256 + threadIdx.x;
    if (e < E) atomicAdd(&cnt[ei[E + e]], 1);
}

__global__ __launch_bounds__(256) void scan1(const int* __restrict__ cnt,
                                             int* __restrict__ offpart,
                                             int* __restrict__ bsum, int n) {
    int t = threadIdx.x, i = blockIdx.x * 256 + t;
    int lane = t & 63, w = t >> 6;
    int v = (i < n) ? cnt[i] : 0;
    int inc = v;
    #pragma unroll
    for (int o = 1; o < 64; o <<= 1) {
        int u = __shfl_up(inc, o, 64);
        if (lane >= o) inc += u;
    }
    __shared__ int wsum[4];
    if (lane == 63) wsum[w] = inc;
    __syncthreads();
    int wadd = 0;
    #pragma unroll
    for (int k = 0; k < 4; ++k) if (k < w) wadd += wsum[k];
    if (i < n) offpart[i] = inc - v + wadd;
    if (t == 255) bsum[blockIdx.x] = inc + wadd;
}

// exclusive scan of up to 1024 block sums, single block of 256 threads
__global__ __launch_bounds__(256) void scan2(const int* __restrict__ bsum,
                                             int* __restrict__ btot, int nb) {
    int t = threadIdx.x, lane = t & 63, w = t >> 6;
    int loc[4]; int s = 0;
    #pragma unroll
    for (int k = 0; k < 4; ++k) {
        int idx = t * 4 + k;
        int v = (idx < nb) ? bsum[idx] : 0;
        loc[k] = s; s += v;
    }
    int inc = s;
    #pragma unroll
    for (int o = 1; o < 64; o <<= 1) {
        int u = __shfl_up(inc, o, 64);
        if (lane >= o) inc += u;
    }
    __shared__ int wsum[4];
    if (lane == 63) wsum[w] = inc;
    __syncthreads();
    int wadd = 0;
    #pragma unroll
    for (int k = 0; k < 4; ++k) if (k < w) wadd += wsum[k];
    int excl = inc - s + wadd;
    #pragma unroll
    for (int k = 0; k < 4; ++k) {
        int idx = t * 4 + k;
        if (idx < nb) btot[idx] = excl + loc[k];
    }
}

__global__ __launch_bounds__(256) void finalize_off(const int* __restrict__ offpart,
                                                    const int* __restrict__ btot,
                                                    int* __restrict__ off, int n, int E) {
    int i = blockIdx.x * 256 + threadIdx.x;
    if (i < n) off[i] = offpart[i] + btot[i >> 8];
    if (i == 0) off[n] = E;
}

__global__ __launch_bounds__(256) void scatter_src(const int* __restrict__ ei, int E,
                                                   const int* __restrict__ off,
                                                   int* __restrict__ cur,
                                                   int* __restrict__ esrc) {
    int e = blockIdx.x * 256 + threadIdx.x;
    if (e >= E) return;
    int d = ei[E + e];
    int pos = off[d] + atomicAdd(&cur[d], 1);
    esrc[pos] = ei[e];
}

// ---------------- per-dst softmax -> alpha (thread per node; avg degree ~1) ----------------
__global__ __launch_bounds__(256) void att_alpha(
    const int* __restrict__ off, const int* __restrict__ esrc,
    const float* __restrict__ a_s, const float* __restrict__ a_d,
    float* __restrict__ alpha_self, float* __restrict__ alpha_e, int N) {
    int d = blockIdx.x * 256 + threadIdx.x;
    if (d >= N) return;
    int beg = off[d], end = off[d + 1];
    f32x4 adv = *(const f32x4*)(a_d + 4 * (long)d);
    f32x4 asd = *(const f32x4*)(a_s + 4 * (long)d);
    float es[4], m[4];
    #pragma unroll
    for (int h = 0; h < 4; ++h) {
        float e = asd[h] + adv[h]; e = e > 0.f ? e : 0.2f * e;
        es[h] = e; m[h] = e;
    }
    for (int j = beg; j < end; ++j) {
        int s = esrc[j];
        f32x4 asv = *(const f32x4*)(a_s + 4 * (long)s);
        #pragma unroll
        for (int h = 0; h < 4; ++h) {
            float e = asv[h] + adv[h]; e = e > 0.f ? e : 0.2f * e;
            m[h] = fmaxf(m[h], e);
        }
    }
    float sum[4];
    #pragma unroll
    for (int h = 0; h < 4; ++h) sum[h] = __expf(es[h] - m[h]);
    for (int j = beg; j < end; ++j) {
        int s = esrc[j];
        f32x4 asv = *(const f32x4*)(a_s + 4 * (long)s);
        #pragma unroll
        for (int h = 0; h < 4; ++h) {
            float e = asv[h] + adv[h]; e = e > 0.f ? e : 0.2f * e;
            sum[h] += __expf(e - m[h]);
        }
    }
    float rs[4];
    #pragma unroll
    for (int h = 0; h < 4; ++h) rs[h] = 1.f / sum[h];
    f32x4 sa;
    #pragma unroll
    for (int h = 0; h < 4; ++h) sa[h] = __expf(es[h] - m[h]) * rs[h];
    *(f32x4*)(alpha_self + 4 * (long)d) = sa;
    for (int j = beg; j < end; ++j) {
        int s = esrc[j];
        f32x4 asv = *(const f32x4*)(a_s + 4 * (long)s);
        f32x4 av;
        #pragma unroll
        for (int h = 0; h < 4; ++h) {
            float e = asv[h] + adv[h]; e = e > 0.f ? e : 0.2f * e;
            av[h] = __expf(e - m[h]) * rs[h];
        }
        *(f32x4*)(alpha_e + 4 * (long)j) = av;
    }
}

// ---------------- gather + bias + LN + relu: 4 nodes/wave, 16 lanes x 16ch ----------------
// hw/out are [N,512] (two dirs concatenated); dirOff selects the 256-ch half.
__global__ __launch_bounds__(256) void gat_gather(
    const int* __restrict__ off, const int* __restrict__ esrc,
    const float* __restrict__ alpha_self, const float* __restrict__ alpha_e,
    const __hip_bfloat16* __restrict__ hw, int dirOff,
    const float* __restrict__ bias, const float* __restrict__ g,
    const float* __restrict__ b,
    __hip_bfloat16* __restrict__ out, int N) {
    int tid = threadIdx.x;
    int lane = tid & 63;
    int grp = lane >> 4, li = lane & 15;
    long d = (long)blockIdx.x * 16 + (tid >> 6) * 4 + grp;
    if (d >= N) return;
    int beg = off[d], end = off[d + 1];
    int head = li >> 2;          // 16 ch/lane -> single head per lane
    int c0 = li * 16;
    float acc[16];
    {   // self loop
        float a = alpha_self[4 * d + head];
        const __hip_bfloat16* r = hw + d * 512 + dirOff + c0;
        bf16x8 h0 = *(const bf16x8*)r;
        bf16x8 h1 = *(const bf16x8*)(r + 8);
        #pragma unroll
        for (int k = 0; k < 8; ++k) {
            acc[k] = a * bf2f(h0[k]);
            acc[8 + k] = a * bf2f(h1[k]);
        }
    }
    for (int j = beg; j < end; ++j) {
        int s = esrc[j];                        // uniform within group
        float a = alpha_e[4 * (long)j + head];
        const __hip_bfloat16* r = hw + (long)s * 512 + dirOff + c0;
        bf16x8 h0 = *(const bf16x8*)r;
        bf16x8 h1 = *(const bf16x8*)(r + 8);
        #pragma unroll
        for (int k = 0; k < 8; ++k) {
            acc[k] += a * bf2f(h0[k]);
            acc[8 + k] += a * bf2f(h1[k]);
        }
    }
    // bias + LN(256) within 16-lane group + relu
    float s1 = 0.f, s2 = 0.f;
    #pragma unroll
    for (int k = 0; k < 16; k += 4) {
        f32x4 bi = *(const f32x4*)(bias + c0 + k);
        #pragma unroll
        for (int u = 0; u < 4; ++u) {
            float v = acc[k + u] + bi[u];
            acc[k + u] = v;
            s1 += v; s2 += v * v;
        }
    }
    #pragma unroll
    for (int o = 1; o < 16; o <<= 1) {
        s1 += __shfl_xor(s1, o, 64);
        s2 += __shfl_xor(s2, o, 64);
    }
    float mean = s1 * (1.f / 256.f);
    float var = s2 * (1.f / 256.f) - mean * mean;
    float inv = rsqrtf(fmaxf(var, 0.f) + 1e-5f);
    __hip_bfloat16 o16[16];
    #pragma unroll
    for (int k = 0; k < 16; k += 4) {
        f32x4 gv = *(const f32x4*)(g + c0 + k);
        f32x4 bv = *(const f32x4*)(b + c0 + k);
        #pragma unroll
        for (int u = 0; u < 4; ++u) {
            float y = (acc[k + u] - mean) * inv * gv[u] + bv[u];
            o16[k + u] = __float2bfloat16(fmaxf(y, 0.f));
        }
    }
    __hip_bfloat16* orow = out + d * 512 + dirOff + c0;
    *(bf16x8*)orow = *(const bf16x8*)o16;
    *(bf16x8*)(orow + 8) = *(const bf16x8*)(o16 + 8);
}

extern "C" void kernel_launch(void* const* d_in, const int* in_sizes, int n_in,
                              void* d_out, int out_size, void* d_ws, size_t ws_size,
                              hipStream_t stream) {
    const float* x      = (const float*)d_in[0];
    const int*   ei_bu  = (const int*)d_in[1];
    const int*   ei_td  = (const int*)d_in[2];
    const float* Wp     = (const float*)d_in[3];
    const float* bp     = (const float*)d_in[4];
    const float* W_bu   = (const float*)d_in[5];
    const float* asrc_bu= (const float*)d_in[6];
    const float* adst_bu= (const float*)d_in[7];
    const float* bias_bu= (const float*)d_in[8];
    const float* W_td   = (const float*)d_in[9];
    const float* asrc_td= (const float*)d_in[10];
    const float* adst_td= (const float*)d_in[11];
    const float* bias_td= (const float*)d_in[12];
    const float* Wf     = (const float*)d_in[13];
    const float* bfv    = (const float*)d_in[14];
    const float* g_bu   = (const float*)d_in[15];
    const float* b_bu   = (const float*)d_in[16];
    const float* g_td   = (const float*)d_in[17];
    const float* b_td   = (const float*)d_in[18];
    const float* g_out  = (const float*)d_in[19];
    const float* b_out  = (const float*)d_in[20];

    const int N = in_sizes[0] / HID;   // 200000
    const int E = in_sizes[1] / 2;     // 200000

    char* ws = (char*)d_ws;
    size_t off0 = 0;
    auto take = [&](size_t bytes) -> char* {
        char* p = ws + off0;
        off0 += (bytes + 255) & ~(size_t)255;
        return p;
    };
    __hip_bfloat16* h_buf = (__hip_bfloat16*)take((size_t)N * 256 * 2);
    __hip_bfloat16* hwcat = (__hip_bfloat16*)take((size_t)N * 512 * 2); // [N][bu|td]
    __hip_bfloat16* xcat  = (__hip_bfloat16*)take((size_t)N * 512 * 2); // [N][xbu|xtd]
    float* aS0   = (float*)take((size_t)N * 16);
    float* aD0   = (float*)take((size_t)N * 16);
    float* aS1   = (float*)take((size_t)N * 16);
    float* aD1   = (float*)take((size_t)N * 16);
    float* alsf  = (float*)take((size_t)N * 16);        // alpha_self [N][4]
    float* ale   = (float*)take((size_t)E * 16);        // alpha_e [E][4] (CSR order)
    int* cnt     = (int*)take((size_t)N * 4);   // cnt and cur adjacent -> one memset
    int* cur     = (int*)take((size_t)N * 4);
    int* offpart = (int*)take((size_t)N * 4);
    int* offarr  = (int*)take((size_t)(N + 1) * 4);
    int* esrc    = (int*)take((size_t)E * 4);
    int* bsum    = (int*)take(1024 * 4);
    int* btot    = (int*)take(1024 * 4);
    __hip_bfloat16* Wpt  = (__hip_bfloat16*)take(256 * 256 * 2);
    __hip_bfloat16* Wcat = (__hip_bfloat16*)take(512 * 256 * 2);  // [512 KO][256 KI]
    __hip_bfloat16* Wft  = (__hip_bfloat16*)take(128 * 512 * 2);  // [128 KO][512 KI]

    transpose_w<<<(256 * 256 + 255) / 256, 256, 0, stream>>>(Wp, Wpt, 256, 256);
    transpose_w<<<(256 * 256 + 255) / 256, 256, 0, stream>>>(W_bu, Wcat, 256, 256);
    transpose_w<<<(256 * 256 + 255) / 256, 256, 0, stream>>>(W_td, Wcat + 256 * 256, 256, 256);
    transpose_w<<<(512 * 128 + 255) / 256, 256, 0, stream>>>(Wf, Wft, 512, 128);

    int gm = (N + 127) / 128;

    // h = relu(x @ Wp + bp)  (A staged from f32 with in-register cvt)
    gemm_tiled<256, 0, 1><<<gm, 512, 0, stream>>>(
        x, nullptr, 256, Wpt, 256, bp, 1, h_buf, 256, 0, nullptr,
        nullptr, nullptr, nullptr, nullptr, nullptr, nullptr, N);

    // hwcat[:, dir*256..] = h @ W_dir  + fused a_src/a_dst scores
    gemm_tiled<256, 1, 0><<<gm, 512, 0, stream>>>(
        nullptr, h_buf, 256, Wcat, 256, nullptr, 0, hwcat, 512, 0, nullptr,
        asrc_bu, adst_bu, aS0, aD0, nullptr, nullptr, N);
    gemm_tiled<256, 1, 0><<<gm, 512, 0, stream>>>(
        nullptr, h_buf, 256, Wcat + 256 * 256, 256, nullptr, 0, hwcat, 512, 256, nullptr,
        asrc_td, adst_td, aS1, aD1, nullptr, nullptr, N);

    const int* eis[2] = {ei_bu, ei_td};
    const float* aSs[2] = {aS0, aS1};
    const float* aDs[2] = {aD0, aD1};
    const float* biases[2]= {bias_bu, bias_td};
    const float* gs[2]    = {g_bu, g_td};
    const float* bs[2]    = {b_bu, b_td};

    int egrid = (E + 255) / 256;
    int ngrid = (N + 255) / 256;
    int nb = (N + 255) / 256;
    for (int dir = 0; dir < 2; ++dir) {
        // CSR build
        hipMemsetAsync(cnt, 0, (size_t)N * 8, stream);   // cnt + cur (adjacent)
        hist_dst<<<egrid, 256, 0, stream>>>(eis[dir], E, cnt);
        scan1<<<nb, 256, 0, stream>>>(cnt, offpart, bsum, N);
        scan2<<<1, 256, 0, stream>>>(bsum, btot, nb);
        finalize_off<<<ngrid, 256, 0, stream>>>(offpart, btot, offarr, N, E);
        scatter_src<<<egrid, 256, 0, stream>>>(eis[dir], E, offarr, cur, esrc);
        // softmax (thread/node), then gather + bias + LN + relu (4 nodes/wave)
        att_alpha<<<ngrid, 256, 0, stream>>>(offarr, esrc, aSs[dir], aDs[dir],
                                             alsf, ale, N);
        gat_gather<<<(N + 15) / 16, 256, 0, stream>>>(offarr, esrc, alsf, ale,
                                                      hwcat, dir * 256,
                                                      biases[dir], gs[dir], bs[dir],
                                                      xcat, N);
    }

    // final: out = L2norm(LN(xcat @ Wf + bf)) fully fused  (gw/bw MUST be non-null)
    gemm_tiled<128, 2, 0><<<gm, 512, 0, stream>>>(
        nullptr, xcat, 512, Wft, 512, bfv, 0, nullptr, 128, 0, (float*)d_out,
        nullptr, nullptr, nullptr, nullptr, g_out, b_out, N);
}